// Round 2
// baseline (812.146 us; speedup 1.0000x reference)
//
#include <hip/hip_runtime.h>
#include <hip/hip_bf16.h>

// ---------- types ----------
typedef __attribute__((ext_vector_type(8))) short short8;
typedef __attribute__((ext_vector_type(4))) float f32x4;

static __device__ __forceinline__ unsigned short f2bf(float x) {
  union { __hip_bfloat16 h; unsigned short u; } cv;
  cv.h = __float2bfloat16(x);
  return cv.u;
}

// ---------- cast fp32 -> bf16, up to 4 concatenated segments ----------
__global__ void cast4_kernel(const float* __restrict__ s0, long n0,
                             const float* __restrict__ s1, long n1,
                             const float* __restrict__ s2, long n2,
                             const float* __restrict__ s3, long n3,
                             unsigned short* __restrict__ dst) {
  long N4 = (n0 + n1 + n2 + n3) >> 2;
  for (long i = blockIdx.x * (long)blockDim.x + threadIdx.x; i < N4;
       i += (long)gridDim.x * blockDim.x) {
    long e = i << 2;
    const float* s; long j = e;
    if (j < n0) s = s0;
    else { j -= n0; if (j < n1) s = s1;
      else { j -= n1; if (j < n2) s = s2;
        else { j -= n2; s = s3; } } }
    float4 v = *reinterpret_cast<const float4*>(s + j);
    ushort4 o;
    o.x = f2bf(v.x); o.y = f2bf(v.y); o.z = f2bf(v.z); o.w = f2bf(v.w);
    *reinterpret_cast<ushort4*>(dst + e) = o;
  }
}

// ---------- transpose-cast: fp32 [R,C] -> bf16 [C,R], batched over z ----------
__global__ __launch_bounds__(256)
void tcast_kernel(const float* __restrict__ in, unsigned short* __restrict__ out,
                  int R, int C, long sIn, long sOut) {
  __shared__ float tile[64][65];
  int z = blockIdx.z;
  const float* src = in + (long)z * sIn;
  unsigned short* dst = out + (long)z * sOut;
  int r0 = blockIdx.y * 64, c0 = blockIdx.x * 64;
  int t = threadIdx.x;
  int lr = t >> 4;          // 0..15
  int lc = (t & 15) * 4;    // 0,4,..,60
#pragma unroll
  for (int j = 0; j < 4; ++j) {
    int r = lr + j * 16;
    float4 v = *reinterpret_cast<const float4*>(src + (long)(r0 + r) * C + c0 + lc);
    tile[r][lc] = v.x; tile[r][lc + 1] = v.y; tile[r][lc + 2] = v.z; tile[r][lc + 3] = v.w;
  }
  __syncthreads();
#pragma unroll
  for (int j = 0; j < 4; ++j) {
    int oc = lr + j * 16;         // out row = c0 + oc (input col)
    ushort4 o;
    o.x = f2bf(tile[lc][oc]);
    o.y = f2bf(tile[lc + 1][oc]);
    o.z = f2bf(tile[lc + 2][oc]);
    o.w = f2bf(tile[lc + 3][oc]);
    *reinterpret_cast<ushort4*>(dst + (long)(c0 + oc) * R + r0 + lc) = o;
  }
}

// ---------- generic NT bf16 MFMA GEMM, m97 structure, TMxTN tile ----------
// OUT: 0=bf16, 1=fp32, 2=fp16. Staging rows clamped to Mclamp/Nclamp; stores
// guarded by cg<Nwrite; DO_STATS accumulates sum/sumsq over cg<Nvalid.
template<int TM, int TN, int OUT, int DO_STATS>
__global__ __launch_bounds__(256)
void gemm_nt(const unsigned short* __restrict__ A,
             const unsigned short* __restrict__ B,
             void* __restrict__ Cp,
             int K, int lda, int ldb, long ldc, int Hdiv,
             long sAb, long sAh, long sBb, long sBh, long sC,
             int nInner, long iA, long iB, float alpha,
             float* __restrict__ stats,
             int Mclamp, int Nclamp, int Nwrite, int Nvalid) {
  constexpr int WM = TM / 32, WN = TN / 32;
  __shared__ unsigned short As[TM * 32];
  __shared__ unsigned short Bs[TN * 32];
  __shared__ float red[8];

  int z = blockIdx.z;
  int b = z / Hdiv, h = z % Hdiv;
  const unsigned short* Ab = A + (long)b * sAb + (long)h * sAh;
  const unsigned short* Bb = B + (long)b * sBb + (long)h * sBh;
  int m0 = blockIdx.y * TM, n0 = blockIdx.x * TN;
  int t = threadIdx.x;
  int lane = t & 63, wave = t >> 6;
  int wm = (wave >> 1) * (TM / 2), wn = (wave & 1) * (TN / 2);
  int l15 = lane & 15, q = lane >> 4;
  int arow = t >> 2, acol = (t & 3) * 8;

  int rA[TM / 64], rB[TN / 64];
#pragma unroll
  for (int r = 0; r < TM / 64; ++r) rA[r] = min(m0 + r * 64 + arow, Mclamp - 1);
#pragma unroll
  for (int r = 0; r < TN / 64; ++r) rB[r] = min(n0 + r * 64 + arow, Nclamp - 1);

  f32x4 acc[WM][WN] = {};

  for (int it = 0; it < nInner; ++it) {
    const unsigned short* Ait = Ab + (long)it * iA;
    const unsigned short* Bit = Bb + (long)it * iB;
    for (int k0 = 0; k0 < K; k0 += 32) {
      __syncthreads();
#pragma unroll
      for (int r = 0; r < TM / 64; ++r)
        __builtin_amdgcn_global_load_lds(
            (const __attribute__((address_space(1))) void*)(Ait + (long)rA[r] * lda + acol + k0),
            (__attribute__((address_space(3))) void*)(As + r * 2048 + t * 8), 16, 0, 0);
#pragma unroll
      for (int r = 0; r < TN / 64; ++r)
        __builtin_amdgcn_global_load_lds(
            (const __attribute__((address_space(1))) void*)(Bit + (long)rB[r] * ldb + acol + k0),
            (__attribute__((address_space(3))) void*)(Bs + r * 2048 + t * 8), 16, 0, 0);
      __syncthreads();
      short8 af[WM], bfr[WN];
#pragma unroll
      for (int i = 0; i < WM; ++i)
        af[i] = *reinterpret_cast<const short8*>(As + (wm + i * 16 + l15) * 32 + q * 8);
#pragma unroll
      for (int j = 0; j < WN; ++j)
        bfr[j] = *reinterpret_cast<const short8*>(Bs + (wn + j * 16 + l15) * 32 + q * 8);
#pragma unroll
      for (int i = 0; i < WM; ++i)
#pragma unroll
        for (int j = 0; j < WN; ++j)
          acc[i][j] = __builtin_amdgcn_mfma_f32_16x16x32_bf16(af[i], bfr[j], acc[i][j], 0, 0, 0);
    }
  }

  long cbase = (long)z * sC;
  float ssum = 0.f, ssq = 0.f;
#pragma unroll
  for (int i = 0; i < WM; ++i)
#pragma unroll
    for (int j = 0; j < WN; ++j)
#pragma unroll
      for (int r = 0; r < 4; ++r) {
        float v = acc[i][j][r] * alpha;
        int rg = m0 + wm + i * 16 + q * 4 + r;
        int cg = n0 + wn + j * 16 + l15;
        if (cg < Nwrite) {
          long idx = cbase + (long)rg * ldc + cg;
          if (OUT == 1) ((float*)Cp)[idx] = v;
          else if (OUT == 2) ((_Float16*)Cp)[idx] = (_Float16)v;
          else ((unsigned short*)Cp)[idx] = f2bf(v);
        }
        if (DO_STATS && cg < Nvalid) { ssum += v; ssq += v * v; }
      }

  if (DO_STATS) {
#pragma unroll
    for (int o = 32; o; o >>= 1) {
      ssum += __shfl_down(ssum, o, 64);
      ssq  += __shfl_down(ssq,  o, 64);
    }
    if (lane == 0) { red[wave] = ssum; red[wave + 4] = ssq; }
    __syncthreads();
    if (t == 0) {
      atomicAdd(stats + (long)z * 2,     red[0] + red[1] + red[2] + red[3]);
      atomicAdd(stats + (long)z * 2 + 1, red[4] + red[5] + red[6] + red[7]);
    }
  }
}

// ---------- 4-branch batched NT GEMM (128x128), branch from blockIdx.x ----------
struct MDesc {
  long aOff[4], bOff[4], cOff[4];
  long sAz[4], sBz[4], sCz[4];
  long iA[4], iB[4];
  int  lda[4], ldb[4], ldcv[4];
  int  Kk[4], Ncl[4], nIn[4];
  int  nstart[4];
  float alpha[4];
};

template<int OUT_F32>
__global__ __launch_bounds__(256)
void gemm_multi(const unsigned short* __restrict__ A0,
                const unsigned short* __restrict__ B0,
                void* __restrict__ Cp, MDesc d) {
  __shared__ unsigned short As[128 * 32];
  __shared__ unsigned short Bs[128 * 32];
  int bx = blockIdx.x;
  int br = (bx >= d.nstart[3]) ? 3 : (bx >= d.nstart[2]) ? 2 : (bx >= d.nstart[1]) ? 1 : 0;
  int z = blockIdx.z;
  int n0 = (bx - d.nstart[br]) * 128;
  int m0 = blockIdx.y * 128;
  int K = d.Kk[br], lda = d.lda[br], ldb = d.ldb[br], ldc = d.ldcv[br];
  int Ncl = d.Ncl[br], nInner = d.nIn[br];
  float alpha = d.alpha[br];
  const unsigned short* Ab = A0 + d.aOff[br] + (long)z * d.sAz[br];
  const unsigned short* Bb = B0 + d.bOff[br] + (long)z * d.sBz[br];

  int t = threadIdx.x, lane = t & 63, wave = t >> 6;
  int wm = (wave >> 1) * 64, wn = (wave & 1) * 64;
  int l15 = lane & 15, q = lane >> 4;
  int arow = t >> 2, acol = (t & 3) * 8;
  int rA0 = m0 + arow, rA1 = m0 + 64 + arow;
  int rB0 = min(n0 + arow, Ncl - 1), rB1 = min(n0 + 64 + arow, Ncl - 1);

  f32x4 acc[4][4] = {};
  for (int it = 0; it < nInner; ++it) {
    const unsigned short* Ait = Ab + (long)it * d.iA[br];
    const unsigned short* Bit = Bb + (long)it * d.iB[br];
    for (int k0 = 0; k0 < K; k0 += 32) {
      __syncthreads();
      __builtin_amdgcn_global_load_lds(
          (const __attribute__((address_space(1))) void*)(Ait + (long)rA0 * lda + acol + k0),
          (__attribute__((address_space(3))) void*)(As + t * 8), 16, 0, 0);
      __builtin_amdgcn_global_load_lds(
          (const __attribute__((address_space(1))) void*)(Ait + (long)rA1 * lda + acol + k0),
          (__attribute__((address_space(3))) void*)(As + 2048 + t * 8), 16, 0, 0);
      __builtin_amdgcn_global_load_lds(
          (const __attribute__((address_space(1))) void*)(Bit + (long)rB0 * ldb + acol + k0),
          (__attribute__((address_space(3))) void*)(Bs + t * 8), 16, 0, 0);
      __builtin_amdgcn_global_load_lds(
          (const __attribute__((address_space(1))) void*)(Bit + (long)rB1 * ldb + acol + k0),
          (__attribute__((address_space(3))) void*)(Bs + 2048 + t * 8), 16, 0, 0);
      __syncthreads();
      short8 af[4], bfr[4];
#pragma unroll
      for (int i = 0; i < 4; ++i)
        af[i] = *reinterpret_cast<const short8*>(As + (wm + i * 16 + l15) * 32 + q * 8);
#pragma unroll
      for (int j = 0; j < 4; ++j)
        bfr[j] = *reinterpret_cast<const short8*>(Bs + (wn + j * 16 + l15) * 32 + q * 8);
#pragma unroll
      for (int i = 0; i < 4; ++i)
#pragma unroll
        for (int j = 0; j < 4; ++j)
          acc[i][j] = __builtin_amdgcn_mfma_f32_16x16x32_bf16(af[i], bfr[j], acc[i][j], 0, 0, 0);
    }
  }

  long cb = d.cOff[br] + (long)z * d.sCz[br];
#pragma unroll
  for (int i = 0; i < 4; ++i)
#pragma unroll
    for (int j = 0; j < 4; ++j)
#pragma unroll
      for (int r = 0; r < 4; ++r) {
        float v = acc[i][j][r] * alpha;
        int rg = m0 + wm + i * 16 + q * 4 + r;
        int cg = n0 + wn + j * 16 + l15;
        if (cg < Ncl) {
          long idx = cb + (long)rg * ldc + cg;
          if (OUT_F32) ((float*)Cp)[idx] = v;
          else ((unsigned short*)Cp)[idx] = f2bf(v);
        }
      }
}

// ---------- instance-norm + softmax over KV=960 (fp16 in, ld 1024), bf16 out ----------
__global__ __launch_bounds__(256)
void norm_softmax_k(const _Float16* __restrict__ S, unsigned short* __restrict__ P,
                    const float* __restrict__ stats, int C, float invCnt) {
  const int KV = 960, LD = 1024;
  long row = blockIdx.x;            // bh*C + c
  int bh = (int)(row / C);
  const _Float16* s = S + row * LD;
  float m1 = stats[bh * 2 + 0] * invCnt;
  float m2 = stats[bh * 2 + 1] * invCnt;
  float rsig = rsqrtf(m2 - m1 * m1 + 1e-5f);
  int t = threadIdx.x;
  float e[4]; float acc = 0.f;
#pragma unroll
  for (int j = 0; j < 4; ++j) {
    int i = t + j * 256;
    if (i < KV) { e[j] = __expf(((float)s[i] - m1) * rsig); acc += e[j]; }
    else e[j] = 0.f;
  }
#pragma unroll
  for (int o = 32; o; o >>= 1) acc += __shfl_down(acc, o, 64);
  __shared__ float red[4];
  if ((t & 63) == 0) red[t >> 6] = acc;
  __syncthreads();
  float inv = 1.0f / (red[0] + red[1] + red[2] + red[3]);
#pragma unroll
  for (int j = 0; j < 4; ++j) {
    int i = t + j * 256;
    if (i < KV) P[row * LD + i] = f2bf(e[j] * inv);
  }
}

// ---------- host ----------
extern "C" void kernel_launch(void* const* d_in, const int* in_sizes, int n_in,
                              void* d_out, int out_size, void* d_ws, size_t ws_size,
                              hipStream_t stream) {
  const float* embs[4] = {(const float*)d_in[0], (const float*)d_in[1],
                          (const float*)d_in[2], (const float*)d_in[3]};
  const float* embA = (const float*)d_in[4];
  const float* Wq1  = (const float*)d_in[5];
  const float* Wq2  = (const float*)d_in[6];
  const float* Wq3  = (const float*)d_in[7];
  const float* Wq4  = (const float*)d_in[8];
  const float* Wk   = (const float*)d_in[9];
  const float* Wv   = (const float*)d_in[10];
  float* out = (float*)d_out;

  char* base = (char*)d_ws;
  size_t off = 0;
  auto take = [&](size_t bytes) -> void* {
    void* p = base + off;
    off += (bytes + 255) & ~(size_t)255;
    return p;
  };
  unsigned short* EA    = (unsigned short*)take(15728640);  // embA bf16 [8][1024][960]
  unsigned short* embAT = (unsigned short*)take(15728640);  // embA^T bf16 [8][960][1024]
  unsigned short* embTc = (unsigned short*)take(15728640);  // concat emb^T bf16 [8][960][1024]
  unsigned short* WQb   = (unsigned short*)take(2785280);   // Wq1..4 bf16
  unsigned short* WKb   = (unsigned short*)take(7372800);   // Wk bf16 [4][960][960]
  unsigned short* WvT   = (unsigned short*)take(7372800);   // Wv^T bf16 [4][960(k)][960(o)]
  unsigned short* WOb   = (unsigned short*)take(696320);    // Wo1..4 bf16
  float*          ST    = (float*)take(1024);
  unsigned short* GT    = (unsigned short*)take(15728640);  // [8][1024(pad)][960]; CT aliases
  unsigned short* Tbuf  = (unsigned short*)take(58982400);  // [32][960][960]
  unsigned short* QTa   = (unsigned short*)take(62914560);  // probs [32][C][1024] per branch
  char*           SCr   = (char*)take(33554432);            // SC fp16 scores; SPW aliases
  _Float16*       SC  = (_Float16*)SCr;
  unsigned short* SPW = (unsigned short*)SCr;               // [8][960][960] bf16
  unsigned short* CT  = GT;                                 // ctx^T [8][1024][960]

  if (ws_size < off) return;  // fail clean instead of faulting

  hipMemsetAsync(ST, 0, 1024, stream);

  const long Cs[4]     = {64, 128, 256, 512};
  const long c0s[4]    = {0, 64, 192, 448};
  const long wqOff[4]  = {0, 16384, 81920, 344064};
  const long woOff[4]  = {0, 4096, 20480, 86016};
  const long outOff[4] = {0, 524288, 1572864, 3670016};
  const long qtOff[4]  = {0, 2097152, 6291456, 14680064};
  const float kscale = 0.0322748612f;  // 1/sqrt(960)

  // plain casts
  cast4_kernel<<<4096, 256, 0, stream>>>(embA, 7864320, embA, 0, embA, 0, embA, 0, EA);
  cast4_kernel<<<1024, 256, 0, stream>>>(Wq1, 16384, Wq2, 65536, Wq3, 262144, Wq4, 1048576, WQb);
  cast4_kernel<<<1024, 256, 0, stream>>>(Wk, 3686400, Wk, 0, Wk, 0, Wk, 0, WKb);
  cast4_kernel<<<512, 256, 0, stream>>>((const float*)d_in[11], 4096, (const float*)d_in[12], 16384,
                                        (const float*)d_in[13], 65536, (const float*)d_in[14], 262144, WOb);
  // transpose-casts
  tcast_kernel<<<dim3(15, 16, 8), 256, 0, stream>>>(embA, embAT, 1024, 960, 983040, 983040);
  for (int i = 0; i < 4; ++i)
    tcast_kernel<<<dim3((int)Cs[i] / 64, 16, 8), 256, 0, stream>>>(
        embs[i], embTc + c0s[i] * 1024, 1024, (int)Cs[i], 1024 * Cs[i], 983040);
  tcast_kernel<<<dim3(15, 15, 4), 256, 0, stream>>>(Wv, WvT, 960, 960, 921600, 921600);

  // GT[b][k][c] = sum_n embA[n,k] * emb_cat[n,c] : M=960(k,pad row write to 1024), N=960(c), K=1024
  gemm_nt<128, 128, 0, 0><<<dim3(8, 8, 8), 256, 0, stream>>>(
      embAT, embTc, GT, 1024, 1024, 1024, 960, 1,
      983040L, 0L, 983040L, 0L, 983040L,
      1, 0L, 0L, 1.0f, nullptr, 960, 960, 960, 0);

  // T[b,h][d][k] = Wq_i,h @ G_i : M=C, N=960, K=C (4 launches)
  for (int i = 0; i < 4; ++i) {
    long C = Cs[i];
    if (C == 64)
      gemm_nt<64, 128, 0, 0><<<dim3(8, 1, 32), 256, 0, stream>>>(
          WQb + wqOff[i], GT + c0s[i], Tbuf + c0s[i] * 960, (int)C, (int)C, 960, 960, 4,
          0L, C * C, 983040L, 0L, 921600L,
          1, 0L, 0L, 1.0f, nullptr, (int)C, 960, 960, 0);
    else
      gemm_nt<128, 128, 0, 0><<<dim3(8, (int)C / 128, 32), 256, 0, stream>>>(
          WQb + wqOff[i], GT + c0s[i], Tbuf + c0s[i] * 960, (int)C, (int)C, 960, 960, 4,
          0L, C * C, 983040L, 0L, 921600L,
          1, 0L, 0L, 1.0f, nullptr, (int)C, 960, 960, 0);
  }

  // scores_i = T_i @ Wk_h^T (fp16 out + stats), then instance-norm+softmax
  for (int i = 0; i < 4; ++i) {
    long C = Cs[i];
    if (C == 64)
      gemm_nt<64, 128, 2, 1><<<dim3(8, 1, 32), 256, 0, stream>>>(
          Tbuf + c0s[i] * 960, WKb, SC, 960, 960, 960, 1024, 4,
          3686400L, 921600L, 0L, 921600L, C * 1024,
          1, 0L, 0L, kscale, ST + i * 64, (int)C, 960, 1024, 960);
    else
      gemm_nt<128, 128, 2, 1><<<dim3(8, (int)C / 128, 32), 256, 0, stream>>>(
          Tbuf + c0s[i] * 960, WKb, SC, 960, 960, 960, 1024, 4,
          3686400L, 921600L, 0L, 921600L, C * 1024,
          1, 0L, 0L, kscale, ST + i * 64, (int)C, 960, 1024, 960);
    norm_softmax_k<<<dim3(32 * (int)C), 256, 0, stream>>>(
        SC, QTa + qtOff[i], ST + i * 64, (int)C, 1.0f / (float)(C * 960));
  }

  // SPW[b][c][k] = (1/4) sum_h probs[b,h][c,:] @ WvT[h][k,:] : M=C, N=960, K=960, nInner=4
  for (int i = 0; i < 4; ++i) {
    long C = Cs[i];
    if (C == 64)
      gemm_nt<64, 128, 0, 0><<<dim3(8, 1, 8), 256, 0, stream>>>(
          QTa + qtOff[i], WvT, SPW + c0s[i] * 960, 960, 1024, 960, 960, 1,
          4L * C * 1024, 0L, 0L, 0L, 921600L,
          4, C * 1024, 921600L, 0.25f, nullptr, (int)C, 960, 960, 0);
    else
      gemm_nt<128, 128, 0, 0><<<dim3(8, (int)C / 128, 8), 256, 0, stream>>>(
          QTa + qtOff[i], WvT, SPW + c0s[i] * 960, 960, 1024, 960, 960, 1,
          4L * C * 1024, 0L, 0L, 0L, 921600L,
          4, C * 1024, 921600L, 0.25f, nullptr, (int)C, 960, 960, 0);
  }

  // CT[b][n][c] = embA[b] @ SPW[b]^T : M=1024, N=960, K=960
  gemm_nt<128, 128, 0, 0><<<dim3(8, 8, 8), 256, 0, stream>>>(
      EA, SPW, CT, 960, 960, 960, 960, 1,
      983040L, 0L, 921600L, 0L, 983040L,
      1, 0L, 0L, 1.0f, nullptr, 1024, 960, 960, 0);

  // out-all: out[b,n,c'] = CT[b][:, branch cols] @ Wo^T, one launch
  {
    MDesc d;
    for (int i = 0; i < 4; ++i) {
      long C = Cs[i];
      d.aOff[i] = c0s[i];       d.sAz[i] = 983040L;          d.iA[i] = 0;
      d.bOff[i] = woOff[i];     d.sBz[i] = 0;                d.iB[i] = 0;
      d.cOff[i] = outOff[i];    d.sCz[i] = 1024L * C;
      d.lda[i] = 960; d.ldb[i] = (int)C; d.ldcv[i] = (int)C;
      d.Kk[i] = (int)C; d.Ncl[i] = (int)C; d.nIn[i] = 1;
      d.alpha[i] = 1.0f;
    }
    d.nstart[0] = 0; d.nstart[1] = 1; d.nstart[2] = 2; d.nstart[3] = 4;
    gemm_multi<1><<<dim3(8, 8, 8), 256, 0, stream>>>(CT, WOb, out, d);
  }
  (void)in_sizes; (void)n_in; (void)out_size;
}

// Round 3
// 737.163 us; speedup vs baseline: 1.1017x; 1.1017x over previous
//
#include <hip/hip_runtime.h>
#include <hip/hip_bf16.h>

// ---------- types ----------
typedef __attribute__((ext_vector_type(8))) short short8;
typedef __attribute__((ext_vector_type(4))) float f32x4;

static __device__ __forceinline__ unsigned short f2bf(float x) {
  union { __hip_bfloat16 h; unsigned short u; } cv;
  cv.h = __float2bfloat16(x);
  return cv.u;
}
static __device__ __forceinline__ float bf2f(unsigned short u) {
  union { unsigned int u; float f; } cv;
  cv.u = ((unsigned int)u) << 16;
  return cv.f;
}

// ---------- cast fp32 -> bf16, up to 4 concatenated segments ----------
__global__ void cast4_kernel(const float* __restrict__ s0, long n0,
                             const float* __restrict__ s1, long n1,
                             const float* __restrict__ s2, long n2,
                             const float* __restrict__ s3, long n3,
                             unsigned short* __restrict__ dst) {
  long N4 = (n0 + n1 + n2 + n3) >> 2;
  for (long i = blockIdx.x * (long)blockDim.x + threadIdx.x; i < N4;
       i += (long)gridDim.x * blockDim.x) {
    long e = i << 2;
    const float* s; long j = e;
    if (j < n0) s = s0;
    else { j -= n0; if (j < n1) s = s1;
      else { j -= n1; if (j < n2) s = s2;
        else { j -= n2; s = s3; } } }
    float4 v = *reinterpret_cast<const float4*>(s + j);
    ushort4 o;
    o.x = f2bf(v.x); o.y = f2bf(v.y); o.z = f2bf(v.z); o.w = f2bf(v.w);
    *reinterpret_cast<ushort4*>(dst + e) = o;
  }
}

// ---------- transpose-cast: fp32 [R,C] -> bf16 [C,R], batched over z ----------
__global__ __launch_bounds__(256)
void tcast_kernel(const float* __restrict__ in, unsigned short* __restrict__ out,
                  int R, int C, long sIn, long sOut) {
  __shared__ float tile[64][65];
  int z = blockIdx.z;
  const float* src = in + (long)z * sIn;
  unsigned short* dst = out + (long)z * sOut;
  int r0 = blockIdx.y * 64, c0 = blockIdx.x * 64;
  int t = threadIdx.x;
  int lr = t >> 4;          // 0..15
  int lc = (t & 15) * 4;    // 0,4,..,60
#pragma unroll
  for (int j = 0; j < 4; ++j) {
    int r = lr + j * 16;
    float4 v = *reinterpret_cast<const float4*>(src + (long)(r0 + r) * C + c0 + lc);
    tile[r][lc] = v.x; tile[r][lc + 1] = v.y; tile[r][lc + 2] = v.z; tile[r][lc + 3] = v.w;
  }
  __syncthreads();
#pragma unroll
  for (int j = 0; j < 4; ++j) {
    int oc = lr + j * 16;
    ushort4 o;
    o.x = f2bf(tile[lc][oc]);
    o.y = f2bf(tile[lc + 1][oc]);
    o.z = f2bf(tile[lc + 2][oc]);
    o.w = f2bf(tile[lc + 3][oc]);
    *reinterpret_cast<ushort4*>(dst + (long)(c0 + oc) * R + r0 + lc) = o;
  }
}

// ---------- y-tile descriptor for branch-aligned tiling ----------
struct YDesc { int m0[8]; int mw[8]; int br[8]; };

// ---------- generic NT bf16 MFMA GEMM, TM=128 x TN tile, 256 threads ----------
// OUT: 0=bf16, 1=fp32, 2=fp16. YD=1: branch-aligned y-tiles from yd (m0/mw/br);
// stats slot = z*8+br*2. YD=0: m0 = blockIdx.y*TM, row guard rg<Mwrite.
template<int TM, int TN, int OUT, int DO_STATS, int YD>
__global__ __launch_bounds__(256)
void gemm_nt(const unsigned short* __restrict__ A,
             const unsigned short* __restrict__ B,
             void* __restrict__ Cp,
             int K, int lda, int ldb, long ldc, int Hdiv,
             long sAb, long sAh, long sBb, long sBh, long sC,
             float alpha, float* __restrict__ stats,
             int Mclamp, int Nclamp, int Mwrite, int Nwrite, YDesc yd) {
  constexpr int WM = TM / 32, WN = TN / 32;
  __shared__ unsigned short As[TM * 32];
  __shared__ unsigned short Bs[TN * 32];
  __shared__ float red[8];

  int z = blockIdx.z;
  int b = z / Hdiv, h = z % Hdiv;
  const unsigned short* Ab = A + (long)b * sAb + (long)h * sAh;
  const unsigned short* Bb = B + (long)b * sBb + (long)h * sBh;
  int y = blockIdx.y;
  int m0 = YD ? yd.m0[y] : y * TM;
  int rowLimit = YD ? (m0 + yd.mw[y]) : Mwrite;
  int n0 = blockIdx.x * TN;
  int t = threadIdx.x;
  int lane = t & 63, wave = t >> 6;
  int wm = (wave >> 1) * (TM / 2), wn = (wave & 1) * (TN / 2);
  int l15 = lane & 15, q = lane >> 4;
  int arow = t >> 2, acol = (t & 3) * 8;

  int rA[TM / 64], rB[TN / 64];
#pragma unroll
  for (int r = 0; r < TM / 64; ++r) rA[r] = min(m0 + r * 64 + arow, Mclamp - 1);
#pragma unroll
  for (int r = 0; r < TN / 64; ++r) rB[r] = min(n0 + r * 64 + arow, Nclamp - 1);

  f32x4 acc[WM][WN] = {};

  for (int k0 = 0; k0 < K; k0 += 32) {
    __syncthreads();
#pragma unroll
    for (int r = 0; r < TM / 64; ++r)
      __builtin_amdgcn_global_load_lds(
          (const __attribute__((address_space(1))) void*)(Ab + (long)rA[r] * lda + acol + k0),
          (__attribute__((address_space(3))) void*)(As + r * 2048 + t * 8), 16, 0, 0);
#pragma unroll
    for (int r = 0; r < TN / 64; ++r)
      __builtin_amdgcn_global_load_lds(
          (const __attribute__((address_space(1))) void*)(Bb + (long)rB[r] * ldb + acol + k0),
          (__attribute__((address_space(3))) void*)(Bs + r * 2048 + t * 8), 16, 0, 0);
    __syncthreads();
    short8 af[WM], bfr[WN];
#pragma unroll
    for (int i = 0; i < WM; ++i)
      af[i] = *reinterpret_cast<const short8*>(As + (wm + i * 16 + l15) * 32 + q * 8);
#pragma unroll
    for (int j = 0; j < WN; ++j)
      bfr[j] = *reinterpret_cast<const short8*>(Bs + (wn + j * 16 + l15) * 32 + q * 8);
#pragma unroll
    for (int i = 0; i < WM; ++i)
#pragma unroll
      for (int j = 0; j < WN; ++j)
        acc[i][j] = __builtin_amdgcn_mfma_f32_16x16x32_bf16(af[i], bfr[j], acc[i][j], 0, 0, 0);
  }

  long cbase = (long)z * sC;
  float ssum = 0.f, ssq = 0.f;
#pragma unroll
  for (int i = 0; i < WM; ++i)
#pragma unroll
    for (int j = 0; j < WN; ++j)
#pragma unroll
      for (int r = 0; r < 4; ++r) {
        float v = acc[i][j][r] * alpha;
        int rg = m0 + wm + i * 16 + q * 4 + r;
        int cg = n0 + wn + j * 16 + l15;
        if (rg < rowLimit && cg < Nwrite) {
          long idx = cbase + (long)rg * ldc + cg;
          if (OUT == 1) ((float*)Cp)[idx] = v;
          else if (OUT == 2) ((_Float16*)Cp)[idx] = (_Float16)v;
          else ((unsigned short*)Cp)[idx] = f2bf(v);
        }
        if (DO_STATS && rg < rowLimit) { ssum += v; ssq += v * v; }
      }

  if (DO_STATS) {
#pragma unroll
    for (int o = 32; o; o >>= 1) {
      ssum += __shfl_down(ssum, o, 64);
      ssq  += __shfl_down(ssq,  o, 64);
    }
    if (lane == 0) { red[wave] = ssum; red[wave + 4] = ssq; }
    __syncthreads();
    if (t == 0) {
      long slot = YD ? ((long)z * 8 + yd.br[y] * 2) : ((long)z * 2);
      atomicAdd(stats + slot,     red[0] + red[1] + red[2] + red[3]);
      atomicAdd(stats + slot + 1, red[4] + red[5] + red[6] + red[7]);
    }
  }
}

// ---------- block-diagonal A GEMM: T[b,h] = Wq_br[h] @ G[b] (per y-tile branch) ----------
struct BDesc { int K[8]; int aRow0[8]; int out0[8]; int mw[8]; int bc[8]; long aOff[8]; long aH[8]; };

__global__ __launch_bounds__(256)
void gemm_bd(const unsigned short* __restrict__ A0,
             const unsigned short* __restrict__ B0,
             unsigned short* __restrict__ Cp,
             int ldb, long sBz, long sC, BDesc d) {
  constexpr int TM = 128, TN = 64, WM = 4, WN = 2;
  __shared__ unsigned short As[TM * 32];
  __shared__ unsigned short Bs[TN * 32];
  int z = blockIdx.z;
  int b = z >> 2, h = z & 3;
  int y = blockIdx.y;
  int K = d.K[y];
  const unsigned short* Ab = A0 + d.aOff[y] + (long)h * d.aH[y];
  const unsigned short* Bb = B0 + (long)b * sBz + d.bc[y];
  int n0 = blockIdx.x * TN;
  int t = threadIdx.x;
  int lane = t & 63, wave = t >> 6;
  int wm = (wave >> 1) * 64, wn = (wave & 1) * 32;
  int l15 = lane & 15, q = lane >> 4;
  int arow = t >> 2, acol = (t & 3) * 8;

  int rA0 = min(d.aRow0[y] + arow, K - 1);
  int rA1 = min(d.aRow0[y] + 64 + arow, K - 1);
  int rB0 = n0 + arow;

  f32x4 acc[WM][WN] = {};
  for (int k0 = 0; k0 < K; k0 += 32) {
    __syncthreads();
    __builtin_amdgcn_global_load_lds(
        (const __attribute__((address_space(1))) void*)(Ab + (long)rA0 * K + acol + k0),
        (__attribute__((address_space(3))) void*)(As + t * 8), 16, 0, 0);
    __builtin_amdgcn_global_load_lds(
        (const __attribute__((address_space(1))) void*)(Ab + (long)rA1 * K + acol + k0),
        (__attribute__((address_space(3))) void*)(As + 2048 + t * 8), 16, 0, 0);
    __builtin_amdgcn_global_load_lds(
        (const __attribute__((address_space(1))) void*)(Bb + (long)rB0 * ldb + acol + k0),
        (__attribute__((address_space(3))) void*)(Bs + t * 8), 16, 0, 0);
    __syncthreads();
    short8 af[WM], bfr[WN];
#pragma unroll
    for (int i = 0; i < WM; ++i)
      af[i] = *reinterpret_cast<const short8*>(As + (wm + i * 16 + l15) * 32 + q * 8);
#pragma unroll
    for (int j = 0; j < WN; ++j)
      bfr[j] = *reinterpret_cast<const short8*>(Bs + (wn + j * 16 + l15) * 32 + q * 8);
#pragma unroll
    for (int i = 0; i < WM; ++i)
#pragma unroll
      for (int j = 0; j < WN; ++j)
        acc[i][j] = __builtin_amdgcn_mfma_f32_16x16x32_bf16(af[i], bfr[j], acc[i][j], 0, 0, 0);
  }

  long cbase = (long)z * sC;
  int mw = d.mw[y], out0 = d.out0[y];
#pragma unroll
  for (int i = 0; i < WM; ++i)
#pragma unroll
    for (int j = 0; j < WN; ++j)
#pragma unroll
      for (int r = 0; r < 4; ++r) {
        int loc = wm + i * 16 + q * 4 + r;
        int cg = n0 + wn + j * 16 + l15;
        if (loc < mw) {
          long idx = cbase + (long)(out0 + loc) * 960 + cg;
          Cp[idx] = f2bf(acc[i][j][r]);
        }
      }
}

// ---------- instance-norm + softmax over KV=960, in-place fp16 -> bf16 ----------
__global__ __launch_bounds__(256)
void norm_softmax_all(_Float16* __restrict__ S, const float* __restrict__ stats) {
  long row = blockIdx.x;            // z*960 + cc
  int z = (int)(row / 960), cc = (int)(row % 960);
  int br = (cc < 64) ? 0 : (cc < 192) ? 1 : (cc < 448) ? 2 : 3;
  int Cbr = (br == 0) ? 64 : (br == 1) ? 128 : (br == 2) ? 256 : 512;
  float invCnt = 1.0f / ((float)Cbr * 960.0f);
  float m1 = stats[z * 8 + br * 2 + 0] * invCnt;
  float m2 = stats[z * 8 + br * 2 + 1] * invCnt;
  float rsig = rsqrtf(m2 - m1 * m1 + 1e-5f);
  _Float16* s = S + row * 960;
  int t = threadIdx.x;
  float e[4]; float acc = 0.f;
#pragma unroll
  for (int j = 0; j < 4; ++j) {
    int i = t + j * 256;
    if (i < 960) { e[j] = __expf(((float)s[i] - m1) * rsig); acc += e[j]; }
    else e[j] = 0.f;
  }
#pragma unroll
  for (int o = 32; o; o >>= 1) acc += __shfl_down(acc, o, 64);
  __shared__ float red[4];
  if ((t & 63) == 0) red[t >> 6] = acc;
  __syncthreads();
  float inv = 1.0f / (red[0] + red[1] + red[2] + red[3]);
  unsigned short* p = (unsigned short*)s;
#pragma unroll
  for (int j = 0; j < 4; ++j) {
    int i = t + j * 256;
    if (i < 960) p[i] = f2bf(e[j] * inv);
  }
}

// ---------- h-reduce: SPW[b] = 0.25 * sum_h SPWh[b*4+h], bf16 ----------
__global__ __launch_bounds__(256)
void hreduce_k(const unsigned short* __restrict__ in, unsigned short* __restrict__ outp) {
  long g = blockIdx.x * 256L + threadIdx.x;   // 921600 threads, 8 elems each
  long e8 = g * 8;
  long b = e8 / 921600;
  long r = e8 % 921600;
  float acc[8] = {};
#pragma unroll
  for (int h = 0; h < 4; ++h) {
    short8 v = *reinterpret_cast<const short8*>(in + (b * 4 + h) * 921600 + r);
#pragma unroll
    for (int k = 0; k < 8; ++k) acc[k] += bf2f((unsigned short)v[k]);
  }
  short8 o;
#pragma unroll
  for (int k = 0; k < 8; ++k) o[k] = (short)f2bf(acc[k] * 0.25f);
  *reinterpret_cast<short8*>(outp + e8) = o;
}

// ---------- 4-branch batched NT GEMM (out-proj), branch from blockIdx.x ----------
struct MDesc {
  long aOff[4], bOff[4], cOff[4];
  long sAz[4], sBz[4], sCz[4];
  long iA[4], iB[4];
  int  lda[4], ldb[4], ldcv[4];
  int  Kk[4], Ncl[4], nIn[4];
  int  nstart[4];
  float alpha[4];
};

template<int OUT_F32>
__global__ __launch_bounds__(256)
void gemm_multi(const unsigned short* __restrict__ A0,
                const unsigned short* __restrict__ B0,
                void* __restrict__ Cp, MDesc d) {
  __shared__ unsigned short As[128 * 32];
  __shared__ unsigned short Bs[128 * 32];
  int bx = blockIdx.x;
  int br = (bx >= d.nstart[3]) ? 3 : (bx >= d.nstart[2]) ? 2 : (bx >= d.nstart[1]) ? 1 : 0;
  int z = blockIdx.z;
  int n0 = (bx - d.nstart[br]) * 128;
  int m0 = blockIdx.y * 128;
  int K = d.Kk[br], lda = d.lda[br], ldb = d.ldb[br], ldc = d.ldcv[br];
  int Ncl = d.Ncl[br], nInner = d.nIn[br];
  float alpha = d.alpha[br];
  const unsigned short* Ab = A0 + d.aOff[br] + (long)z * d.sAz[br];
  const unsigned short* Bb = B0 + d.bOff[br] + (long)z * d.sBz[br];

  int t = threadIdx.x, lane = t & 63, wave = t >> 6;
  int wm = (wave >> 1) * 64, wn = (wave & 1) * 64;
  int l15 = lane & 15, q = lane >> 4;
  int arow = t >> 2, acol = (t & 3) * 8;
  int rA0 = m0 + arow, rA1 = m0 + 64 + arow;
  int rB0 = min(n0 + arow, Ncl - 1), rB1 = min(n0 + 64 + arow, Ncl - 1);

  f32x4 acc[4][4] = {};
  for (int it = 0; it < nInner; ++it) {
    const unsigned short* Ait = Ab + (long)it * d.iA[br];
    const unsigned short* Bit = Bb + (long)it * d.iB[br];
    for (int k0 = 0; k0 < K; k0 += 32) {
      __syncthreads();
      __builtin_amdgcn_global_load_lds(
          (const __attribute__((address_space(1))) void*)(Ait + (long)rA0 * lda + acol + k0),
          (__attribute__((address_space(3))) void*)(As + t * 8), 16, 0, 0);
      __builtin_amdgcn_global_load_lds(
          (const __attribute__((address_space(1))) void*)(Ait + (long)rA1 * lda + acol + k0),
          (__attribute__((address_space(3))) void*)(As + 2048 + t * 8), 16, 0, 0);
      __builtin_amdgcn_global_load_lds(
          (const __attribute__((address_space(1))) void*)(Bit + (long)rB0 * ldb + acol + k0),
          (__attribute__((address_space(3))) void*)(Bs + t * 8), 16, 0, 0);
      __builtin_amdgcn_global_load_lds(
          (const __attribute__((address_space(1))) void*)(Bit + (long)rB1 * ldb + acol + k0),
          (__attribute__((address_space(3))) void*)(Bs + 2048 + t * 8), 16, 0, 0);
      __syncthreads();
      short8 af[4], bfr[4];
#pragma unroll
      for (int i = 0; i < 4; ++i)
        af[i] = *reinterpret_cast<const short8*>(As + (wm + i * 16 + l15) * 32 + q * 8);
#pragma unroll
      for (int j = 0; j < 4; ++j)
        bfr[j] = *reinterpret_cast<const short8*>(Bs + (wn + j * 16 + l15) * 32 + q * 8);
#pragma unroll
      for (int i = 0; i < 4; ++i)
#pragma unroll
        for (int j = 0; j < 4; ++j)
          acc[i][j] = __builtin_amdgcn_mfma_f32_16x16x32_bf16(af[i], bfr[j], acc[i][j], 0, 0, 0);
    }
  }

  long cb = d.cOff[br] + (long)z * d.sCz[br];
#pragma unroll
  for (int i = 0; i < 4; ++i)
#pragma unroll
    for (int j = 0; j < 4; ++j)
#pragma unroll
      for (int r = 0; r < 4; ++r) {
        float v = acc[i][j][r] * alpha;
        int rg = m0 + wm + i * 16 + q * 4 + r;
        int cg = n0 + wn + j * 16 + l15;
        if (cg < Ncl) {
          long idx = cb + (long)rg * ldc + cg;
          if (OUT_F32) ((float*)Cp)[idx] = v;
          else ((unsigned short*)Cp)[idx] = f2bf(v);
        }
      }
}

// ---------- host ----------
extern "C" void kernel_launch(void* const* d_in, const int* in_sizes, int n_in,
                              void* d_out, int out_size, void* d_ws, size_t ws_size,
                              hipStream_t stream) {
  const float* embs[4] = {(const float*)d_in[0], (const float*)d_in[1],
                          (const float*)d_in[2], (const float*)d_in[3]};
  const float* embA = (const float*)d_in[4];
  const float* Wq1  = (const float*)d_in[5];
  const float* Wq2  = (const float*)d_in[6];
  const float* Wq3  = (const float*)d_in[7];
  const float* Wq4  = (const float*)d_in[8];
  const float* Wk   = (const float*)d_in[9];
  const float* Wv   = (const float*)d_in[10];
  float* out = (float*)d_out;

  char* base = (char*)d_ws;
  size_t off = 0;
  auto take = [&](size_t bytes) -> void* {
    void* p = base + off;
    off += (bytes + 255) & ~(size_t)255;
    return p;
  };
  unsigned short* EA    = (unsigned short*)take(15728640);  // embA bf16 [8][1024][960]
  unsigned short* embAT = (unsigned short*)take(15728640);  // embA^T [8][960][1024]; CT aliases
  unsigned short* embTc = (unsigned short*)take(15728640);  // concat emb^T [8][960][1024]
  unsigned short* WQb   = (unsigned short*)take(2785280);   // Wq1..4 bf16
  unsigned short* WKb   = (unsigned short*)take(7372800);   // Wk bf16 [4][960][960]
  unsigned short* WvT   = (unsigned short*)take(7372800);   // Wv^T [4][960][960]
  unsigned short* WOb   = (unsigned short*)take(696320);    // Wo1..4 bf16
  float*          ST    = (float*)take(1024);               // stats [32][4][2] f32
  unsigned short* GT    = (unsigned short*)take(14745600);  // G [8][960][960]; SPW aliases
  unsigned short* Tbuf  = (unsigned short*)take(58982400);  // T [32][960][960]; SPWh aliases
  char*           SCr   = (char*)take(58982400);            // scores fp16 -> probs bf16 in place
  _Float16*       SC    = (_Float16*)SCr;
  unsigned short* PR    = (unsigned short*)SCr;             // probs bf16 [32][960][960]
  unsigned short* SPWh  = Tbuf;                             // [32][960][960] (T dead after scores)
  unsigned short* SPW   = GT;                               // [8][960][960]  (G dead after T)
  unsigned short* CT    = embAT;                            // [8][1024][960] (embAT dead after G)

  if (ws_size < off) return;  // fail clean instead of faulting

  hipMemsetAsync(ST, 0, 1024, stream);

  const long Cs[4]     = {64, 128, 256, 512};
  const long c0s[4]    = {0, 64, 192, 448};
  const long woOff[4]  = {0, 4096, 20480, 86016};
  const long outOff[4] = {0, 524288, 1572864, 3670016};
  const float kscale = 0.0322748612f;  // 1/sqrt(960)
  YDesc ydDummy = {};

  // plain casts
  cast4_kernel<<<4096, 256, 0, stream>>>(embA, 7864320, embA, 0, embA, 0, embA, 0, EA);
  cast4_kernel<<<1024, 256, 0, stream>>>(Wq1, 16384, Wq2, 65536, Wq3, 262144, Wq4, 1048576, WQb);
  cast4_kernel<<<1024, 256, 0, stream>>>(Wk, 3686400, Wk, 0, Wk, 0, Wk, 0, WKb);
  cast4_kernel<<<512, 256, 0, stream>>>((const float*)d_in[11], 4096, (const float*)d_in[12], 16384,
                                        (const float*)d_in[13], 65536, (const float*)d_in[14], 262144, WOb);
  // transpose-casts
  tcast_kernel<<<dim3(15, 16, 8), 256, 0, stream>>>(embA, embAT, 1024, 960, 983040, 983040);
  for (int i = 0; i < 4; ++i)
    tcast_kernel<<<dim3((int)Cs[i] / 64, 16, 8), 256, 0, stream>>>(
        embs[i], embTc + c0s[i] * 1024, 1024, (int)Cs[i], 1024 * Cs[i], 983040);
  tcast_kernel<<<dim3(15, 15, 4), 256, 0, stream>>>(Wv, WvT, 960, 960, 921600, 921600);

  // G[b][k][c] = sum_n embA[n,k]*emb_cat[n,c] : M=960, N=960, K=1024, z=8
  gemm_nt<128, 64, 0, 0, 0><<<dim3(15, 8, 8), 256, 0, stream>>>(
      embAT, embTc, GT, 1024, 1024, 1024, 960, 1,
      983040L, 0L, 983040L, 0L, 921600L,
      1.0f, nullptr, 960, 960, 960, 960, ydDummy);

  // T[b,h][cc][k] = Wq_br[h] @ G[b] (block-diagonal over branch rows), one launch
  {
    BDesc d;
    const int brOf[8]  = {0, 1, 2, 2, 3, 3, 3, 3};
    const int ar0[8]   = {0, 0, 0, 128, 0, 128, 256, 384};
    const long wqOff[4] = {0, 16384, 81920, 344064};
    for (int y = 0; y < 8; ++y) {
      int br = brOf[y];
      int Ci = (int)Cs[br];
      d.K[y] = Ci;
      d.aRow0[y] = ar0[y];
      d.out0[y] = (int)c0s[br] + ar0[y];
      d.mw[y] = (br == 0) ? 64 : 128;
      d.bc[y] = (int)c0s[br];
      d.aOff[y] = wqOff[br];
      d.aH[y] = (long)Ci * Ci;
    }
    gemm_bd<<<dim3(15, 8, 32), 256, 0, stream>>>(WQb, GT, Tbuf, 960, 921600L, 921600L, d);
  }

  // scores[b,h][cc][o] = kscale * T[b,h] @ Wk[h]^T, fp16 out + per-branch stats, one launch
  {
    YDesc yd;
    const int m0s[8] = {0, 64, 192, 320, 448, 576, 704, 832};
    const int mws[8] = {64, 128, 128, 128, 128, 128, 128, 128};
    const int brs[8] = {0, 1, 2, 2, 3, 3, 3, 3};
    for (int y = 0; y < 8; ++y) { yd.m0[y] = m0s[y]; yd.mw[y] = mws[y]; yd.br[y] = brs[y]; }
    gemm_nt<128, 64, 2, 1, 1><<<dim3(15, 8, 32), 256, 0, stream>>>(
        Tbuf, WKb, SC, 960, 960, 960, 960, 4,
        3686400L, 921600L, 0L, 921600L, 921600L,
        kscale, ST, 960, 960, 960, 960, yd);
  }

  // instance-norm + softmax, in place (fp16 scores -> bf16 probs), one launch
  norm_softmax_all<<<dim3(32 * 960), 256, 0, stream>>>(SC, ST);

  // SPWh[b,h][cc][k] = probs[b,h] @ WvT[h] : M=960, N=960, K=960, z=32
  gemm_nt<128, 64, 0, 0, 0><<<dim3(15, 8, 32), 256, 0, stream>>>(
      PR, WvT, SPWh, 960, 960, 960, 960, 4,
      3686400L, 921600L, 0L, 921600L, 921600L,
      1.0f, nullptr, 960, 960, 960, 960, ydDummy);

  // SPW[b] = 0.25 * sum_h SPWh[b,h]
  hreduce_k<<<dim3(3600), 256, 0, stream>>>(SPWh, SPW);

  // CT[b][n][cc] = embA[b] @ SPW[b]^T : M=1024, N=960, K=960, z=8
  gemm_nt<128, 64, 0, 0, 0><<<dim3(15, 8, 8), 256, 0, stream>>>(
      EA, SPW, CT, 960, 960, 960, 960, 1,
      983040L, 0L, 921600L, 0L, 983040L,
      1.0f, nullptr, 1024, 960, 1024, 960, ydDummy);

  // out-all: out[b,n,c'] = CT[b][:, branch cols] @ Wo^T, one launch
  {
    MDesc d;
    for (int i = 0; i < 4; ++i) {
      long C = Cs[i];
      d.aOff[i] = c0s[i];       d.sAz[i] = 983040L;          d.iA[i] = 0;
      d.bOff[i] = woOff[i];     d.sBz[i] = 0;                d.iB[i] = 0;
      d.cOff[i] = outOff[i];    d.sCz[i] = 1024L * C;
      d.lda[i] = 960; d.ldb[i] = (int)C; d.ldcv[i] = (int)C;
      d.Kk[i] = (int)C; d.Ncl[i] = (int)C; d.nIn[i] = 1;
      d.alpha[i] = 1.0f;
    }
    d.nstart[0] = 0; d.nstart[1] = 1; d.nstart[2] = 2; d.nstart[3] = 4;
    gemm_multi<1><<<dim3(8, 8, 8), 256, 0, stream>>>(CT, WOb, out, d);
  }
  (void)in_sizes; (void)n_in; (void)out_size;
}

// Round 4
// 550.635 us; speedup vs baseline: 1.4749x; 1.3387x over previous
//
#include <hip/hip_runtime.h>
#include <hip/hip_bf16.h>

// ---------- types ----------
typedef __attribute__((ext_vector_type(8))) short short8;
typedef __attribute__((ext_vector_type(4))) float f32x4;

static __device__ __forceinline__ unsigned short f2bf(float x) {
  union { __hip_bfloat16 h; unsigned short u; } cv;
  cv.h = __float2bfloat16(x);
  return cv.u;
}
static __device__ __forceinline__ float bf2f(unsigned short u) {
  union { unsigned int u; float f; } cv;
  cv.u = ((unsigned int)u) << 16;
  return cv.f;
}

// XCD-chunked swizzle: contiguous logical-tile ranges per XCD (requires nwg%8==0).
// HW round-robins linear block id across 8 XCDs; this inverse map gives XCD k
// the logical tiles [k*chunk, (k+1)*chunk) so x-adjacent tiles (sharing an
// A-panel) hit one XCD's L2.   [T1; mechanism verified by 545MB FETCH in r3]
static __device__ __forceinline__ void xcd_swizzle(unsigned& bx, unsigned& by, unsigned& bz) {
  unsigned nwg = gridDim.x * gridDim.y * gridDim.z;
  unsigned lin = blockIdx.x + gridDim.x * (blockIdx.y + gridDim.y * blockIdx.z);
  unsigned chunk = nwg >> 3;
  lin = (lin & 7) * chunk + (lin >> 3);
  bx = lin % gridDim.x;
  unsigned tmp = lin / gridDim.x;
  by = tmp % gridDim.y;
  bz = tmp / gridDim.y;
}

// ---------- cast fp32 -> bf16, up to 4 concatenated segments ----------
__global__ void cast4_kernel(const float* __restrict__ s0, long n0,
                             const float* __restrict__ s1, long n1,
                             const float* __restrict__ s2, long n2,
                             const float* __restrict__ s3, long n3,
                             unsigned short* __restrict__ dst) {
  long N4 = (n0 + n1 + n2 + n3) >> 2;
  for (long i = blockIdx.x * (long)blockDim.x + threadIdx.x; i < N4;
       i += (long)gridDim.x * blockDim.x) {
    long e = i << 2;
    const float* s; long j = e;
    if (j < n0) s = s0;
    else { j -= n0; if (j < n1) s = s1;
      else { j -= n1; if (j < n2) s = s2;
        else { j -= n2; s = s3; } } }
    float4 v = *reinterpret_cast<const float4*>(s + j);
    ushort4 o;
    o.x = f2bf(v.x); o.y = f2bf(v.y); o.z = f2bf(v.z); o.w = f2bf(v.w);
    *reinterpret_cast<ushort4*>(dst + e) = o;
  }
}

// ---------- transpose-cast: fp32 [R,C] -> bf16 [C,R], batched over z ----------
__global__ __launch_bounds__(256)
void tcast_kernel(const float* __restrict__ in, unsigned short* __restrict__ out,
                  int R, int C, long sIn, long sOut) {
  __shared__ float tile[64][65];
  int z = blockIdx.z;
  const float* src = in + (long)z * sIn;
  unsigned short* dst = out + (long)z * sOut;
  int r0 = blockIdx.y * 64, c0 = blockIdx.x * 64;
  int t = threadIdx.x;
  int lr = t >> 4;          // 0..15
  int lc = (t & 15) * 4;    // 0,4,..,60
#pragma unroll
  for (int j = 0; j < 4; ++j) {
    int r = lr + j * 16;
    float4 v = *reinterpret_cast<const float4*>(src + (long)(r0 + r) * C + c0 + lc);
    tile[r][lc] = v.x; tile[r][lc + 1] = v.y; tile[r][lc + 2] = v.z; tile[r][lc + 3] = v.w;
  }
  __syncthreads();
#pragma unroll
  for (int j = 0; j < 4; ++j) {
    int oc = lr + j * 16;
    ushort4 o;
    o.x = f2bf(tile[lc][oc]);
    o.y = f2bf(tile[lc + 1][oc]);
    o.z = f2bf(tile[lc + 2][oc]);
    o.w = f2bf(tile[lc + 3][oc]);
    *reinterpret_cast<ushort4*>(dst + (long)(c0 + oc) * R + r0 + lc) = o;
  }
}

// ---------- y-tile descriptor for branch-aligned tiling ----------
struct YDesc { int m0[8]; int mw[8]; int br[8]; };

// ---------- generic NT bf16 MFMA GEMM, TM x TN tile, 256 threads ----------
// OUT: 0=bf16, 1=fp32, 2=fp16. YD=1: branch-aligned y-tiles from yd (m0/mw/br);
// stats slot = z*8+br*2. YD=0: m0 = by*TM, row guard rg<Mwrite.
// Stats guarded by cg<Nvalid. All launches must have nwg%8==0 (xcd_swizzle).
template<int TM, int TN, int OUT, int DO_STATS, int YD>
__global__ __launch_bounds__(256)
void gemm_nt(const unsigned short* __restrict__ A,
             const unsigned short* __restrict__ B,
             void* __restrict__ Cp,
             int K, int lda, int ldb, long ldc, int Hdiv,
             long sAb, long sAh, long sBb, long sBh, long sC,
             float alpha, float* __restrict__ stats,
             int Mclamp, int Nclamp, int Mwrite, int Nwrite, int Nvalid, YDesc yd) {
  constexpr int WM = TM / 32, WN = TN / 32;
  __shared__ unsigned short As[TM * 32];
  __shared__ unsigned short Bs[TN * 32];
  __shared__ float red[8];

  unsigned bxu, byu, bzu;
  xcd_swizzle(bxu, byu, bzu);
  int z = (int)bzu;
  int b = z / Hdiv, h = z % Hdiv;
  const unsigned short* Ab = A + (long)b * sAb + (long)h * sAh;
  const unsigned short* Bb = B + (long)b * sBb + (long)h * sBh;
  int y = (int)byu;
  int m0 = YD ? yd.m0[y] : y * TM;
  int rowLimit = YD ? (m0 + yd.mw[y]) : Mwrite;
  int n0 = (int)bxu * TN;
  int t = threadIdx.x;
  int lane = t & 63, wave = t >> 6;
  int wm = (wave >> 1) * (TM / 2), wn = (wave & 1) * (TN / 2);
  int l15 = lane & 15, q = lane >> 4;
  int arow = t >> 2, acol = (t & 3) * 8;

  int rA[TM / 64], rB[TN / 64];
#pragma unroll
  for (int r = 0; r < TM / 64; ++r) rA[r] = min(m0 + r * 64 + arow, Mclamp - 1);
#pragma unroll
  for (int r = 0; r < TN / 64; ++r) rB[r] = min(n0 + r * 64 + arow, Nclamp - 1);

  f32x4 acc[WM][WN] = {};

  for (int k0 = 0; k0 < K; k0 += 32) {
    __syncthreads();
#pragma unroll
    for (int r = 0; r < TM / 64; ++r)
      __builtin_amdgcn_global_load_lds(
          (const __attribute__((address_space(1))) void*)(Ab + (long)rA[r] * lda + acol + k0),
          (__attribute__((address_space(3))) void*)(As + r * 2048 + t * 8), 16, 0, 0);
#pragma unroll
    for (int r = 0; r < TN / 64; ++r)
      __builtin_amdgcn_global_load_lds(
          (const __attribute__((address_space(1))) void*)(Bb + (long)rB[r] * ldb + acol + k0),
          (__attribute__((address_space(3))) void*)(Bs + r * 2048 + t * 8), 16, 0, 0);
    __syncthreads();
    short8 af[WM], bfr[WN];
#pragma unroll
    for (int i = 0; i < WM; ++i)
      af[i] = *reinterpret_cast<const short8*>(As + (wm + i * 16 + l15) * 32 + q * 8);
#pragma unroll
    for (int j = 0; j < WN; ++j)
      bfr[j] = *reinterpret_cast<const short8*>(Bs + (wn + j * 16 + l15) * 32 + q * 8);
#pragma unroll
    for (int i = 0; i < WM; ++i)
#pragma unroll
      for (int j = 0; j < WN; ++j)
        acc[i][j] = __builtin_amdgcn_mfma_f32_16x16x32_bf16(af[i], bfr[j], acc[i][j], 0, 0, 0);
  }

  long cbase = (long)z * sC;
  float ssum = 0.f, ssq = 0.f;
#pragma unroll
  for (int i = 0; i < WM; ++i)
#pragma unroll
    for (int j = 0; j < WN; ++j)
#pragma unroll
      for (int r = 0; r < 4; ++r) {
        float v = acc[i][j][r] * alpha;
        int rg = m0 + wm + i * 16 + q * 4 + r;
        int cg = n0 + wn + j * 16 + l15;
        if (rg < rowLimit && cg < Nwrite) {
          long idx = cbase + (long)rg * ldc + cg;
          if (OUT == 1) ((float*)Cp)[idx] = v;
          else if (OUT == 2) ((_Float16*)Cp)[idx] = (_Float16)v;
          else ((unsigned short*)Cp)[idx] = f2bf(v);
        }
        if (DO_STATS && rg < rowLimit && cg < Nvalid) { ssum += v; ssq += v * v; }
      }

  if (DO_STATS) {
#pragma unroll
    for (int o = 32; o; o >>= 1) {
      ssum += __shfl_down(ssum, o, 64);
      ssq  += __shfl_down(ssq,  o, 64);
    }
    if (lane == 0) { red[wave] = ssum; red[wave + 4] = ssq; }
    __syncthreads();
    if (t == 0) {
      long slot = YD ? ((long)z * 8 + yd.br[y] * 2) : ((long)z * 2);
      atomicAdd(stats + slot,     red[0] + red[1] + red[2] + red[3]);
      atomicAdd(stats + slot + 1, red[4] + red[5] + red[6] + red[7]);
    }
  }
}

// ---------- block-diagonal A GEMM: T[b,h] = Wq_br[h] @ G[b] (per y-tile branch) ----------
struct BDesc { int K[8]; int aRow0[8]; int out0[8]; int mw[8]; int bc[8]; long aOff[8]; long aH[8]; };

__global__ __launch_bounds__(256)
void gemm_bd(const unsigned short* __restrict__ A0,
             const unsigned short* __restrict__ B0,
             unsigned short* __restrict__ Cp,
             int ldb, long sBz, long sC, BDesc d) {
  constexpr int TM = 128, TN = 64, WM = 4, WN = 2;
  __shared__ unsigned short As[TM * 32];
  __shared__ unsigned short Bs[TN * 32];
  unsigned bxu, byu, bzu;
  xcd_swizzle(bxu, byu, bzu);
  int z = (int)bzu;
  int b = z >> 2, h = z & 3;
  int y = (int)byu;
  int K = d.K[y];
  const unsigned short* Ab = A0 + d.aOff[y] + (long)h * d.aH[y];
  const unsigned short* Bb = B0 + (long)b * sBz + d.bc[y];
  int n0 = (int)bxu * TN;
  int t = threadIdx.x;
  int lane = t & 63, wave = t >> 6;
  int wm = (wave >> 1) * 64, wn = (wave & 1) * 32;
  int l15 = lane & 15, q = lane >> 4;
  int arow = t >> 2, acol = (t & 3) * 8;

  int rA0 = min(d.aRow0[y] + arow, K - 1);
  int rA1 = min(d.aRow0[y] + 64 + arow, K - 1);
  int rB0 = n0 + arow;

  f32x4 acc[WM][WN] = {};
  for (int k0 = 0; k0 < K; k0 += 32) {
    __syncthreads();
    __builtin_amdgcn_global_load_lds(
        (const __attribute__((address_space(1))) void*)(Ab + (long)rA0 * K + acol + k0),
        (__attribute__((address_space(3))) void*)(As + t * 8), 16, 0, 0);
    __builtin_amdgcn_global_load_lds(
        (const __attribute__((address_space(1))) void*)(Ab + (long)rA1 * K + acol + k0),
        (__attribute__((address_space(3))) void*)(As + 2048 + t * 8), 16, 0, 0);
    __builtin_amdgcn_global_load_lds(
        (const __attribute__((address_space(1))) void*)(Bb + (long)rB0 * ldb + acol + k0),
        (__attribute__((address_space(3))) void*)(Bs + t * 8), 16, 0, 0);
    __syncthreads();
    short8 af[WM], bfr[WN];
#pragma unroll
    for (int i = 0; i < WM; ++i)
      af[i] = *reinterpret_cast<const short8*>(As + (wm + i * 16 + l15) * 32 + q * 8);
#pragma unroll
    for (int j = 0; j < WN; ++j)
      bfr[j] = *reinterpret_cast<const short8*>(Bs + (wn + j * 16 + l15) * 32 + q * 8);
#pragma unroll
    for (int i = 0; i < WM; ++i)
#pragma unroll
      for (int j = 0; j < WN; ++j)
        acc[i][j] = __builtin_amdgcn_mfma_f32_16x16x32_bf16(af[i], bfr[j], acc[i][j], 0, 0, 0);
  }

  long cbase = (long)z * sC;
  int mw = d.mw[y], out0 = d.out0[y];
#pragma unroll
  for (int i = 0; i < WM; ++i)
#pragma unroll
    for (int j = 0; j < WN; ++j)
#pragma unroll
      for (int r = 0; r < 4; ++r) {
        int loc = wm + i * 16 + q * 4 + r;
        int cg = n0 + wn + j * 16 + l15;
        if (loc < mw) {
          long idx = cbase + (long)(out0 + loc) * 960 + cg;
          Cp[idx] = f2bf(acc[i][j][r]);
        }
      }
}

// ---------- instance-norm + softmax over KV=960, in-place fp16 -> bf16 ----------
__global__ __launch_bounds__(256)
void norm_softmax_all(_Float16* __restrict__ S, const float* __restrict__ stats) {
  long row = blockIdx.x;            // z*960 + cc
  int z = (int)(row / 960), cc = (int)(row % 960);
  int br = (cc < 64) ? 0 : (cc < 192) ? 1 : (cc < 448) ? 2 : 3;
  int Cbr = (br == 0) ? 64 : (br == 1) ? 128 : (br == 2) ? 256 : 512;
  float invCnt = 1.0f / ((float)Cbr * 960.0f);
  float m1 = stats[z * 8 + br * 2 + 0] * invCnt;
  float m2 = stats[z * 8 + br * 2 + 1] * invCnt;
  float rsig = rsqrtf(m2 - m1 * m1 + 1e-5f);
  _Float16* s = S + row * 960;
  int t = threadIdx.x;
  float e[4]; float acc = 0.f;
#pragma unroll
  for (int j = 0; j < 4; ++j) {
    int i = t + j * 256;
    if (i < 960) { e[j] = __expf(((float)s[i] - m1) * rsig); acc += e[j]; }
    else e[j] = 0.f;
  }
#pragma unroll
  for (int o = 32; o; o >>= 1) acc += __shfl_down(acc, o, 64);
  __shared__ float red[4];
  if ((t & 63) == 0) red[t >> 6] = acc;
  __syncthreads();
  float inv = 1.0f / (red[0] + red[1] + red[2] + red[3]);
  unsigned short* p = (unsigned short*)s;
#pragma unroll
  for (int j = 0; j < 4; ++j) {
    int i = t + j * 256;
    if (i < 960) p[i] = f2bf(e[j] * inv);
  }
}

// ---------- h-reduce: SPW[b] = 0.25 * sum_h SPWh[b*4+h], bf16 ----------
__global__ __launch_bounds__(256)
void hreduce_k(const unsigned short* __restrict__ in, unsigned short* __restrict__ outp) {
  long g = blockIdx.x * 256L + threadIdx.x;   // 921600 threads, 8 elems each
  long e8 = g * 8;
  long b = e8 / 921600;
  long r = e8 % 921600;
  float acc[8] = {};
#pragma unroll
  for (int h = 0; h < 4; ++h) {
    short8 v = *reinterpret_cast<const short8*>(in + (b * 4 + h) * 921600 + r);
#pragma unroll
    for (int k = 0; k < 8; ++k) acc[k] += bf2f((unsigned short)v[k]);
  }
  short8 o;
#pragma unroll
  for (int k = 0; k < 8; ++k) o[k] = (short)f2bf(acc[k] * 0.25f);
  *reinterpret_cast<short8*>(outp + e8) = o;
}

// ---------- 4-branch batched NT GEMM (out-proj), branch from bx ----------
struct MDesc {
  long aOff[4], bOff[4], cOff[4];
  long sAz[4], sBz[4], sCz[4];
  long iA[4], iB[4];
  int  lda[4], ldb[4], ldcv[4];
  int  Kk[4], Ncl[4], nIn[4];
  int  nstart[4];
  float alpha[4];
};

template<int OUT_F32>
__global__ __launch_bounds__(256)
void gemm_multi(const unsigned short* __restrict__ A0,
                const unsigned short* __restrict__ B0,
                void* __restrict__ Cp, MDesc d) {
  __shared__ unsigned short As[128 * 32];
  __shared__ unsigned short Bs[128 * 32];
  unsigned bxu, byu, bzu;
  xcd_swizzle(bxu, byu, bzu);
  int bx = (int)bxu;
  int br = (bx >= d.nstart[3]) ? 3 : (bx >= d.nstart[2]) ? 2 : (bx >= d.nstart[1]) ? 1 : 0;
  int z = (int)bzu;
  int n0 = (bx - d.nstart[br]) * 128;
  int m0 = (int)byu * 128;
  int K = d.Kk[br], lda = d.lda[br], ldb = d.ldb[br], ldc = d.ldcv[br];
  int Ncl = d.Ncl[br], nInner = d.nIn[br];
  float alpha = d.alpha[br];
  const unsigned short* Ab = A0 + d.aOff[br] + (long)z * d.sAz[br];
  const unsigned short* Bb = B0 + d.bOff[br] + (long)z * d.sBz[br];

  int t = threadIdx.x, lane = t & 63, wave = t >> 6;
  int wm = (wave >> 1) * 64, wn = (wave & 1) * 64;
  int l15 = lane & 15, q = lane >> 4;
  int arow = t >> 2, acol = (t & 3) * 8;
  int rA0 = m0 + arow, rA1 = m0 + 64 + arow;
  int rB0 = min(n0 + arow, Ncl - 1), rB1 = min(n0 + 64 + arow, Ncl - 1);

  f32x4 acc[4][4] = {};
  for (int it = 0; it < nInner; ++it) {
    const unsigned short* Ait = Ab + (long)it * d.iA[br];
    const unsigned short* Bit = Bb + (long)it * d.iB[br];
    for (int k0 = 0; k0 < K; k0 += 32) {
      __syncthreads();
      __builtin_amdgcn_global_load_lds(
          (const __attribute__((address_space(1))) void*)(Ait + (long)rA0 * lda + acol + k0),
          (__attribute__((address_space(3))) void*)(As + t * 8), 16, 0, 0);
      __builtin_amdgcn_global_load_lds(
          (const __attribute__((address_space(1))) void*)(Ait + (long)rA1 * lda + acol + k0),
          (__attribute__((address_space(3))) void*)(As + 2048 + t * 8), 16, 0, 0);
      __builtin_amdgcn_global_load_lds(
          (const __attribute__((address_space(1))) void*)(Bit + (long)rB0 * ldb + acol + k0),
          (__attribute__((address_space(3))) void*)(Bs + t * 8), 16, 0, 0);
      __builtin_amdgcn_global_load_lds(
          (const __attribute__((address_space(1))) void*)(Bit + (long)rB1 * ldb + acol + k0),
          (__attribute__((address_space(3))) void*)(Bs + 2048 + t * 8), 16, 0, 0);
      __syncthreads();
      short8 af[4], bfr[4];
#pragma unroll
      for (int i = 0; i < 4; ++i)
        af[i] = *reinterpret_cast<const short8*>(As + (wm + i * 16 + l15) * 32 + q * 8);
#pragma unroll
      for (int j = 0; j < 4; ++j)
        bfr[j] = *reinterpret_cast<const short8*>(Bs + (wn + j * 16 + l15) * 32 + q * 8);
#pragma unroll
      for (int i = 0; i < 4; ++i)
#pragma unroll
        for (int j = 0; j < 4; ++j)
          acc[i][j] = __builtin_amdgcn_mfma_f32_16x16x32_bf16(af[i], bfr[j], acc[i][j], 0, 0, 0);
    }
  }

  long cb = d.cOff[br] + (long)z * d.sCz[br];
#pragma unroll
  for (int i = 0; i < 4; ++i)
#pragma unroll
    for (int j = 0; j < 4; ++j)
#pragma unroll
      for (int r = 0; r < 4; ++r) {
        float v = acc[i][j][r] * alpha;
        int rg = m0 + wm + i * 16 + q * 4 + r;
        int cg = n0 + wn + j * 16 + l15;
        if (cg < Ncl) {
          long idx = cb + (long)rg * ldc + cg;
          if (OUT_F32) ((float*)Cp)[idx] = v;
          else ((unsigned short*)Cp)[idx] = f2bf(v);
        }
      }
}

// ---------- host ----------
extern "C" void kernel_launch(void* const* d_in, const int* in_sizes, int n_in,
                              void* d_out, int out_size, void* d_ws, size_t ws_size,
                              hipStream_t stream) {
  const float* embs[4] = {(const float*)d_in[0], (const float*)d_in[1],
                          (const float*)d_in[2], (const float*)d_in[3]};
  const float* embA = (const float*)d_in[4];
  const float* Wq1  = (const float*)d_in[5];
  const float* Wq2  = (const float*)d_in[6];
  const float* Wq3  = (const float*)d_in[7];
  const float* Wq4  = (const float*)d_in[8];
  const float* Wk   = (const float*)d_in[9];
  const float* Wv   = (const float*)d_in[10];
  float* out = (float*)d_out;

  char* base = (char*)d_ws;
  size_t off = 0;
  auto take = [&](size_t bytes) -> void* {
    void* p = base + off;
    off += (bytes + 255) & ~(size_t)255;
    return p;
  };
  unsigned short* EA    = (unsigned short*)take(15728640);  // embA bf16 [8][1024][960]
  unsigned short* embAT = (unsigned short*)take(15728640);  // embA^T [8][960][1024]; CT aliases
  unsigned short* embTc = (unsigned short*)take(15728640);  // concat emb^T [8][960][1024]
  unsigned short* WQb   = (unsigned short*)take(2785280);   // Wq1..4 bf16
  unsigned short* WKb   = (unsigned short*)take(7372800);   // Wk bf16 [4][960][960]
  unsigned short* WvT   = (unsigned short*)take(7372800);   // Wv^T [4][960][960]
  unsigned short* WOb   = (unsigned short*)take(696320);    // Wo1..4 bf16
  float*          ST    = (float*)take(1024);               // stats [32][4][2] f32
  unsigned short* GT    = (unsigned short*)take(14745600);  // G [8][960][960]; SPW aliases
  unsigned short* Tbuf  = (unsigned short*)take(58982400);  // T [32][960][960]; SPWh aliases
  char*           SCr   = (char*)take(58982400);            // scores fp16 -> probs bf16 in place
  _Float16*       SC    = (_Float16*)SCr;
  unsigned short* PR    = (unsigned short*)SCr;             // probs bf16 [32][960][960]
  unsigned short* SPWh  = Tbuf;                             // [32][960][960] (T dead after scores)
  unsigned short* SPW   = GT;                               // [8][960][960]  (G dead after T)
  unsigned short* CT    = embAT;                            // [8][1024][960] (embAT dead after G)

  if (ws_size < off) return;  // fail clean instead of faulting

  hipMemsetAsync(ST, 0, 1024, stream);

  const long Cs[4]     = {64, 128, 256, 512};
  const long c0s[4]    = {0, 64, 192, 448};
  const long woOff[4]  = {0, 4096, 20480, 86016};
  const long outOff[4] = {0, 524288, 1572864, 3670016};
  const float kscale = 0.0322748612f;  // 1/sqrt(960)
  YDesc ydDummy = {};

  // plain casts
  cast4_kernel<<<4096, 256, 0, stream>>>(embA, 7864320, embA, 0, embA, 0, embA, 0, EA);
  cast4_kernel<<<1024, 256, 0, stream>>>(Wq1, 16384, Wq2, 65536, Wq3, 262144, Wq4, 1048576, WQb);
  cast4_kernel<<<1024, 256, 0, stream>>>(Wk, 3686400, Wk, 0, Wk, 0, Wk, 0, WKb);
  cast4_kernel<<<512, 256, 0, stream>>>((const float*)d_in[11], 4096, (const float*)d_in[12], 16384,
                                        (const float*)d_in[13], 65536, (const float*)d_in[14], 262144, WOb);
  // transpose-casts
  tcast_kernel<<<dim3(15, 16, 8), 256, 0, stream>>>(embA, embAT, 1024, 960, 983040, 983040);
  for (int i = 0; i < 4; ++i)
    tcast_kernel<<<dim3((int)Cs[i] / 64, 16, 8), 256, 0, stream>>>(
        embs[i], embTc + c0s[i] * 1024, 1024, (int)Cs[i], 1024 * Cs[i], 983040);
  tcast_kernel<<<dim3(15, 15, 4), 256, 0, stream>>>(Wv, WvT, 960, 960, 921600, 921600);

  // G[b][k][c] = sum_n embA[n,k]*emb_cat[n,c] : M=960, N=960, K=1024, z=8 (512 blocks)
  gemm_nt<128, 128, 0, 0, 0><<<dim3(8, 8, 8), 256, 0, stream>>>(
      embAT, embTc, GT, 1024, 1024, 1024, 960, 1,
      983040L, 0L, 983040L, 0L, 921600L,
      1.0f, nullptr, 960, 960, 960, 960, 0, ydDummy);

  // T[b,h][cc][k] = Wq_br[h] @ G[b] (block-diagonal over branch rows), one launch
  {
    BDesc d;
    const int brOf[8]  = {0, 1, 2, 2, 3, 3, 3, 3};
    const int ar0[8]   = {0, 0, 0, 128, 0, 128, 256, 384};
    const long wqOff[4] = {0, 16384, 81920, 344064};
    for (int y = 0; y < 8; ++y) {
      int br = brOf[y];
      int Ci = (int)Cs[br];
      d.K[y] = Ci;
      d.aRow0[y] = ar0[y];
      d.out0[y] = (int)c0s[br] + ar0[y];
      d.mw[y] = (br == 0) ? 64 : 128;
      d.bc[y] = (int)c0s[br];
      d.aOff[y] = wqOff[br];
      d.aH[y] = (long)Ci * Ci;
    }
    gemm_bd<<<dim3(15, 8, 32), 256, 0, stream>>>(WQb, GT, Tbuf, 960, 921600L, 921600L, d);
  }

  // scores[b,h][cc][o] = kscale * T[b,h] @ Wk[h]^T, fp16 out + per-branch stats (2048 blocks)
  {
    YDesc yd;
    const int m0s[8] = {0, 64, 192, 320, 448, 576, 704, 832};
    const int mws[8] = {64, 128, 128, 128, 128, 128, 128, 128};
    const int brs[8] = {0, 1, 2, 2, 3, 3, 3, 3};
    for (int y = 0; y < 8; ++y) { yd.m0[y] = m0s[y]; yd.mw[y] = mws[y]; yd.br[y] = brs[y]; }
    gemm_nt<128, 128, 2, 1, 1><<<dim3(8, 8, 32), 256, 0, stream>>>(
        Tbuf, WKb, SC, 960, 960, 960, 960, 4,
        3686400L, 921600L, 0L, 921600L, 921600L,
        kscale, ST, 960, 960, 960, 960, 960, yd);
  }

  // instance-norm + softmax, in place (fp16 scores -> bf16 probs), one launch
  norm_softmax_all<<<dim3(32 * 960), 256, 0, stream>>>(SC, ST);

  // SPWh[b,h][cc][k] = probs[b,h] @ WvT[h] : M=960, N=960, K=960, z=32 (2048 blocks)
  gemm_nt<128, 128, 0, 0, 0><<<dim3(8, 8, 32), 256, 0, stream>>>(
      PR, WvT, SPWh, 960, 960, 960, 960, 4,
      3686400L, 921600L, 0L, 921600L, 921600L,
      1.0f, nullptr, 960, 960, 960, 960, 0, ydDummy);

  // SPW[b] = 0.25 * sum_h SPWh[b,h]
  hreduce_k<<<dim3(3600), 256, 0, stream>>>(SPWh, SPW);

  // CT[b][n][cc] = embA[b] @ SPW[b]^T : M=1024, N=960, K=960, z=8 (512 blocks)
  gemm_nt<128, 128, 0, 0, 0><<<dim3(8, 8, 8), 256, 0, stream>>>(
      EA, SPW, CT, 960, 960, 960, 960, 1,
      983040L, 0L, 921600L, 0L, 983040L,
      1.0f, nullptr, 1024, 960, 1024, 960, 0, ydDummy);

  // out-all: out[b,n,c'] = CT[b][:, branch cols] @ Wo^T, one launch (512 blocks)
  {
    MDesc d;
    for (int i = 0; i < 4; ++i) {
      long C = Cs[i];
      d.aOff[i] = c0s[i];       d.sAz[i] = 983040L;          d.iA[i] = 0;
      d.bOff[i] = woOff[i];     d.sBz[i] = 0;                d.iB[i] = 0;
      d.cOff[i] = outOff[i];    d.sCz[i] = 1024L * C;
      d.lda[i] = 960; d.ldb[i] = (int)C; d.ldcv[i] = (int)C;
      d.Kk[i] = (int)C; d.Ncl[i] = (int)C; d.nIn[i] = 1;
      d.alpha[i] = 1.0f;
    }
    d.nstart[0] = 0; d.nstart[1] = 1; d.nstart[2] = 2; d.nstart[3] = 4;
    gemm_multi<1><<<dim3(8, 8, 8), 256, 0, stream>>>(CT, WOb, out, d);
  }
  (void)in_sizes; (void)n_in; (void)out_size;
}

// Round 5
// 513.798 us; speedup vs baseline: 1.5807x; 1.0717x over previous
//
#include <hip/hip_runtime.h>
#include <hip/hip_bf16.h>

// ---------- types ----------
typedef __attribute__((ext_vector_type(8))) short short8;
typedef __attribute__((ext_vector_type(4))) float f32x4;

static __device__ __forceinline__ unsigned short f2bf(float x) {
  union { __hip_bfloat16 h; unsigned short u; } cv;
  cv.h = __float2bfloat16(x);
  return cv.u;
}

// XCD-chunked swizzle (T1): contiguous logical-tile ranges per XCD (nwg%8==0).
// Verified r3->r4: FETCH 545MB -> 65MB on the scores/SPW GEMMs.
static __device__ __forceinline__ void xcd_swizzle(unsigned& bx, unsigned& by, unsigned& bz) {
  unsigned nwg = gridDim.x * gridDim.y * gridDim.z;
  unsigned lin = blockIdx.x + gridDim.x * (blockIdx.y + gridDim.y * blockIdx.z);
  unsigned chunk = nwg >> 3;
  lin = (lin & 7) * chunk + (lin >> 3);
  bx = lin % gridDim.x;
  unsigned tmp = lin / gridDim.x;
  by = tmp % gridDim.y;
  bz = tmp / gridDim.y;
}

// ---------- cast fp32 -> bf16, up to 4 concatenated segments ----------
__global__ void cast4_kernel(const float* __restrict__ s0, long n0,
                             const float* __restrict__ s1, long n1,
                             const float* __restrict__ s2, long n2,
                             const float* __restrict__ s3, long n3,
                             unsigned short* __restrict__ dst) {
  long N4 = (n0 + n1 + n2 + n3) >> 2;
  for (long i = blockIdx.x * (long)blockDim.x + threadIdx.x; i < N4;
       i += (long)gridDim.x * blockDim.x) {
    long e = i << 2;
    const float* s; long j = e;
    if (j < n0) s = s0;
    else { j -= n0; if (j < n1) s = s1;
      else { j -= n1; if (j < n2) s = s2;
        else { j -= n2; s = s3; } } }
    float4 v = *reinterpret_cast<const float4*>(s + j);
    ushort4 o;
    o.x = f2bf(v.x); o.y = f2bf(v.y); o.z = f2bf(v.z); o.w = f2bf(v.w);
    *reinterpret_cast<ushort4*>(dst + e) = o;
  }
}

// ---------- transpose-cast: fp32 [R,C] -> bf16 [C,R], batched over z ----------
__global__ __launch_bounds__(256)
void tcast_kernel(const float* __restrict__ in, unsigned short* __restrict__ out,
                  int R, int C, long sIn, long sOut) {
  __shared__ float tile[64][65];
  int z = blockIdx.z;
  const float* src = in + (long)z * sIn;
  unsigned short* dst = out + (long)z * sOut;
  int r0 = blockIdx.y * 64, c0 = blockIdx.x * 64;
  int t = threadIdx.x;
  int lr = t >> 4;          // 0..15
  int lc = (t & 15) * 4;    // 0,4,..,60
#pragma unroll
  for (int j = 0; j < 4; ++j) {
    int r = lr + j * 16;
    float4 v = *reinterpret_cast<const float4*>(src + (long)(r0 + r) * C + c0 + lc);
    tile[r][lc] = v.x; tile[r][lc + 1] = v.y; tile[r][lc + 2] = v.z; tile[r][lc + 3] = v.w;
  }
  __syncthreads();
#pragma unroll
  for (int j = 0; j < 4; ++j) {
    int oc = lr + j * 16;
    ushort4 o;
    o.x = f2bf(tile[lc][oc]);
    o.y = f2bf(tile[lc + 1][oc]);
    o.z = f2bf(tile[lc + 2][oc]);
    o.w = f2bf(tile[lc + 3][oc]);
    *reinterpret_cast<ushort4*>(dst + (long)(c0 + oc) * R + r0 + lc) = o;
  }
}

// ---------- y-tile descriptor for branch-aligned tiling ----------
struct YDesc { int m0[8]; int mw[8]; int br[8]; };

// ---------- generic NT bf16 MFMA GEMM, TM x TN tile, 256 threads ----------
// 2-phase double-buffered staging (T3-minimum): issue next K-step's
// global_load_lds BEFORE computing current step; single __syncthreads per step
// (drains vmcnt+lgkmcnt -> race-free). nInner folds a reduction (e.g. heads)
// by walking A/B base pointers by iA/iB every K columns.
template<int TM, int TN, int OUT, int DO_STATS, int YD>
__global__ __launch_bounds__(256)
void gemm_nt(const unsigned short* __restrict__ A,
             const unsigned short* __restrict__ B,
             void* __restrict__ Cp,
             int K, int lda, int ldb, long ldc, int Hdiv,
             long sAb, long sAh, long sBb, long sBh, long sC,
             int nInner, long iA, long iB,
             float alpha, float* __restrict__ stats,
             int Mclamp, int Nclamp, int Mwrite, int Nwrite, int Nvalid, YDesc yd) {
  constexpr int WM = TM / 32, WN = TN / 32;
  __shared__ unsigned short As[2][TM * 32];
  __shared__ unsigned short Bs[2][TN * 32];
  __shared__ float red[8];

  unsigned bxu, byu, bzu;
  xcd_swizzle(bxu, byu, bzu);
  int z = (int)bzu;
  int b = z / Hdiv, h = z % Hdiv;
  const unsigned short* Ab = A + (long)b * sAb + (long)h * sAh;
  const unsigned short* Bb = B + (long)b * sBb + (long)h * sBh;
  int y = (int)byu;
  int m0 = YD ? yd.m0[y] : y * TM;
  int rowLimit = YD ? (m0 + yd.mw[y]) : Mwrite;
  int n0 = (int)bxu * TN;
  int t = threadIdx.x;
  int lane = t & 63, wave = t >> 6;
  int wm = (wave >> 1) * (TM / 2), wn = (wave & 1) * (TN / 2);
  int l15 = lane & 15, q = lane >> 4;
  int arow = t >> 2, acol = (t & 3) * 8;

  int rA[TM / 64], rB[TN / 64];
#pragma unroll
  for (int r = 0; r < TM / 64; ++r) rA[r] = min(m0 + r * 64 + arow, Mclamp - 1);
#pragma unroll
  for (int r = 0; r < TN / 64; ++r) rB[r] = min(n0 + r * 64 + arow, Nclamp - 1);

  int kSteps = K >> 5;
  int nt = nInner * kSteps;
  const unsigned short* Asrc = Ab;
  const unsigned short* Bsrc = Bb;
  int kk = 0;

  auto stage = [&](int bufSel) {
#pragma unroll
    for (int r = 0; r < TM / 64; ++r)
      __builtin_amdgcn_global_load_lds(
          (const __attribute__((address_space(1))) void*)(Asrc + (long)rA[r] * lda + acol + kk),
          (__attribute__((address_space(3))) void*)(&As[bufSel][r * 2048 + t * 8]), 16, 0, 0);
#pragma unroll
    for (int r = 0; r < TN / 64; ++r)
      __builtin_amdgcn_global_load_lds(
          (const __attribute__((address_space(1))) void*)(Bsrc + (long)rB[r] * ldb + acol + kk),
          (__attribute__((address_space(3))) void*)(&Bs[bufSel][r * 2048 + t * 8]), 16, 0, 0);
  };
  auto advance = [&]() { kk += 32; if (kk >= K) { kk = 0; Asrc += iA; Bsrc += iB; } };

  f32x4 acc[WM][WN] = {};
  stage(0);
  advance();
  __syncthreads();
  for (int s = 0; s < nt; ++s) {
    int cur = s & 1;
    if (s + 1 < nt) { stage(cur ^ 1); advance(); }
    short8 af[WM], bfr[WN];
#pragma unroll
    for (int i = 0; i < WM; ++i)
      af[i] = *reinterpret_cast<const short8*>(&As[cur][(wm + i * 16 + l15) * 32 + q * 8]);
#pragma unroll
    for (int j = 0; j < WN; ++j)
      bfr[j] = *reinterpret_cast<const short8*>(&Bs[cur][(wn + j * 16 + l15) * 32 + q * 8]);
#pragma unroll
    for (int i = 0; i < WM; ++i)
#pragma unroll
      for (int j = 0; j < WN; ++j)
        acc[i][j] = __builtin_amdgcn_mfma_f32_16x16x32_bf16(af[i], bfr[j], acc[i][j], 0, 0, 0);
    __syncthreads();
  }

  long cbase = (long)z * sC;
  float ssum = 0.f, ssq = 0.f;
#pragma unroll
  for (int i = 0; i < WM; ++i)
#pragma unroll
    for (int j = 0; j < WN; ++j)
#pragma unroll
      for (int r = 0; r < 4; ++r) {
        float v = acc[i][j][r] * alpha;
        int rg = m0 + wm + i * 16 + q * 4 + r;
        int cg = n0 + wn + j * 16 + l15;
        if (rg < rowLimit && cg < Nwrite) {
          long idx = cbase + (long)rg * ldc + cg;
          if (OUT == 1) ((float*)Cp)[idx] = v;
          else if (OUT == 2) ((_Float16*)Cp)[idx] = (_Float16)v;
          else ((unsigned short*)Cp)[idx] = f2bf(v);
        }
        if (DO_STATS && rg < rowLimit && cg < Nvalid) { ssum += v; ssq += v * v; }
      }

  if (DO_STATS) {
#pragma unroll
    for (int o = 32; o; o >>= 1) {
      ssum += __shfl_down(ssum, o, 64);
      ssq  += __shfl_down(ssq,  o, 64);
    }
    if (lane == 0) { red[wave] = ssum; red[wave + 4] = ssq; }
    __syncthreads();
    if (t == 0) {
      long slot = YD ? ((long)z * 8 + yd.br[y] * 2) : ((long)z * 2);
      atomicAdd(stats + slot,     red[0] + red[1] + red[2] + red[3]);
      atomicAdd(stats + slot + 1, red[4] + red[5] + red[6] + red[7]);
    }
  }
}

// ---------- block-diagonal A GEMM: T[b,h] = Wq_br[h] @ G[b] (per y-tile branch) ----------
struct BDesc { int K[8]; int aRow0[8]; int out0[8]; int mw[8]; int bc[8]; long aOff[8]; long aH[8]; };

__global__ __launch_bounds__(256)
void gemm_bd(const unsigned short* __restrict__ A0,
             const unsigned short* __restrict__ B0,
             unsigned short* __restrict__ Cp,
             int ldb, long sBz, long sC, BDesc d) {
  constexpr int TM = 128, TN = 64, WM = 4, WN = 2;
  __shared__ unsigned short As[2][TM * 32];
  __shared__ unsigned short Bs[2][TN * 32];
  unsigned bxu, byu, bzu;
  xcd_swizzle(bxu, byu, bzu);
  int z = (int)bzu;
  int b = z >> 2, h = z & 3;
  int y = (int)byu;
  int K = d.K[y];
  const unsigned short* Ab = A0 + d.aOff[y] + (long)h * d.aH[y];
  const unsigned short* Bb = B0 + (long)b * sBz + d.bc[y];
  int n0 = (int)bxu * TN;
  int t = threadIdx.x;
  int lane = t & 63, wave = t >> 6;
  int wm = (wave >> 1) * 64, wn = (wave & 1) * 32;
  int l15 = lane & 15, q = lane >> 4;
  int arow = t >> 2, acol = (t & 3) * 8;

  int rA0 = min(d.aRow0[y] + arow, K - 1);
  int rA1 = min(d.aRow0[y] + 64 + arow, K - 1);
  int rB0 = n0 + arow;

  int kk = 0;
  auto stage = [&](int bufSel) {
    __builtin_amdgcn_global_load_lds(
        (const __attribute__((address_space(1))) void*)(Ab + (long)rA0 * K + acol + kk),
        (__attribute__((address_space(3))) void*)(&As[bufSel][t * 8]), 16, 0, 0);
    __builtin_amdgcn_global_load_lds(
        (const __attribute__((address_space(1))) void*)(Ab + (long)rA1 * K + acol + kk),
        (__attribute__((address_space(3))) void*)(&As[bufSel][2048 + t * 8]), 16, 0, 0);
    __builtin_amdgcn_global_load_lds(
        (const __attribute__((address_space(1))) void*)(Bb + (long)rB0 * ldb + acol + kk),
        (__attribute__((address_space(3))) void*)(&Bs[bufSel][t * 8]), 16, 0, 0);
  };

  int nt = K >> 5;
  f32x4 acc[WM][WN] = {};
  stage(0);
  kk += 32;
  __syncthreads();
  for (int s = 0; s < nt; ++s) {
    int cur = s & 1;
    if (s + 1 < nt) { stage(cur ^ 1); kk += 32; }
    short8 af[WM], bfr[WN];
#pragma unroll
    for (int i = 0; i < WM; ++i)
      af[i] = *reinterpret_cast<const short8*>(&As[cur][(wm + i * 16 + l15) * 32 + q * 8]);
#pragma unroll
    for (int j = 0; j < WN; ++j)
      bfr[j] = *reinterpret_cast<const short8*>(&Bs[cur][(wn + j * 16 + l15) * 32 + q * 8]);
#pragma unroll
    for (int i = 0; i < WM; ++i)
#pragma unroll
      for (int j = 0; j < WN; ++j)
        acc[i][j] = __builtin_amdgcn_mfma_f32_16x16x32_bf16(af[i], bfr[j], acc[i][j], 0, 0, 0);
    __syncthreads();
  }

  long cbase = (long)z * sC;
  int mw = d.mw[y], out0 = d.out0[y];
#pragma unroll
  for (int i = 0; i < WM; ++i)
#pragma unroll
    for (int j = 0; j < WN; ++j)
#pragma unroll
      for (int r = 0; r < 4; ++r) {
        int loc = wm + i * 16 + q * 4 + r;
        int cg = n0 + wn + j * 16 + l15;
        if (loc < mw) {
          long idx = cbase + (long)(out0 + loc) * 960 + cg;
          Cp[idx] = f2bf(acc[i][j][r]);
        }
      }
}

// ---------- instance-norm + softmax over KV=960, in-place fp16 -> bf16 ----------
__global__ __launch_bounds__(256)
void norm_softmax_all(_Float16* __restrict__ S, const float* __restrict__ stats) {
  long row = blockIdx.x;            // z*960 + cc
  int z = (int)(row / 960), cc = (int)(row % 960);
  int br = (cc < 64) ? 0 : (cc < 192) ? 1 : (cc < 448) ? 2 : 3;
  int Cbr = (br == 0) ? 64 : (br == 1) ? 128 : (br == 2) ? 256 : 512;
  float invCnt = 1.0f / ((float)Cbr * 960.0f);
  float m1 = stats[z * 8 + br * 2 + 0] * invCnt;
  float m2 = stats[z * 8 + br * 2 + 1] * invCnt;
  float rsig = rsqrtf(m2 - m1 * m1 + 1e-5f);
  _Float16* s = S + row * 960;
  int t = threadIdx.x;
  float e[4]; float acc = 0.f;
#pragma unroll
  for (int j = 0; j < 4; ++j) {
    int i = t + j * 256;
    if (i < 960) { e[j] = __expf(((float)s[i] - m1) * rsig); acc += e[j]; }
    else e[j] = 0.f;
  }
#pragma unroll
  for (int o = 32; o; o >>= 1) acc += __shfl_down(acc, o, 64);
  __shared__ float red[4];
  if ((t & 63) == 0) red[t >> 6] = acc;
  __syncthreads();
  float inv = 1.0f / (red[0] + red[1] + red[2] + red[3]);
  unsigned short* p = (unsigned short*)s;
#pragma unroll
  for (int j = 0; j < 4; ++j) {
    int i = t + j * 256;
    if (i < 960) p[i] = f2bf(e[j] * inv);
  }
}

// ---------- 4-branch batched NT GEMM (out-proj), branch from bx ----------
struct MDesc {
  long aOff[4], bOff[4], cOff[4];
  long sAz[4], sBz[4], sCz[4];
  long iA[4], iB[4];
  int  lda[4], ldb[4], ldcv[4];
  int  Kk[4], Ncl[4], nIn[4];
  int  nstart[4];
  float alpha[4];
};

template<int OUT_F32>
__global__ __launch_bounds__(256)
void gemm_multi(const unsigned short* __restrict__ A0,
                const unsigned short* __restrict__ B0,
                void* __restrict__ Cp, MDesc d) {
  __shared__ unsigned short As[2][128 * 32];
  __shared__ unsigned short Bs[2][128 * 32];
  unsigned bxu, byu, bzu;
  xcd_swizzle(bxu, byu, bzu);
  int bx = (int)bxu;
  int br = (bx >= d.nstart[3]) ? 3 : (bx >= d.nstart[2]) ? 2 : (bx >= d.nstart[1]) ? 1 : 0;
  int z = (int)bzu;
  int n0 = (bx - d.nstart[br]) * 128;
  int m0 = (int)byu * 128;
  int K = d.Kk[br], lda = d.lda[br], ldb = d.ldb[br], ldc = d.ldcv[br];
  int Ncl = d.Ncl[br], nInner = d.nIn[br];
  long iA = d.iA[br], iB = d.iB[br];
  float alpha = d.alpha[br];
  const unsigned short* Ab = A0 + d.aOff[br] + (long)z * d.sAz[br];
  const unsigned short* Bb = B0 + d.bOff[br] + (long)z * d.sBz[br];

  int t = threadIdx.x, lane = t & 63, wave = t >> 6;
  int wm = (wave >> 1) * 64, wn = (wave & 1) * 64;
  int l15 = lane & 15, q = lane >> 4;
  int arow = t >> 2, acol = (t & 3) * 8;
  int rA0 = m0 + arow, rA1 = m0 + 64 + arow;
  int rB0 = min(n0 + arow, Ncl - 1), rB1 = min(n0 + 64 + arow, Ncl - 1);

  const unsigned short* Asrc = Ab;
  const unsigned short* Bsrc = Bb;
  int kk = 0;
  auto stage = [&](int bufSel) {
    __builtin_amdgcn_global_load_lds(
        (const __attribute__((address_space(1))) void*)(Asrc + (long)rA0 * lda + acol + kk),
        (__attribute__((address_space(3))) void*)(&As[bufSel][t * 8]), 16, 0, 0);
    __builtin_amdgcn_global_load_lds(
        (const __attribute__((address_space(1))) void*)(Asrc + (long)rA1 * lda + acol + kk),
        (__attribute__((address_space(3))) void*)(&As[bufSel][2048 + t * 8]), 16, 0, 0);
    __builtin_amdgcn_global_load_lds(
        (const __attribute__((address_space(1))) void*)(Bsrc + (long)rB0 * ldb + acol + kk),
        (__attribute__((address_space(3))) void*)(&Bs[bufSel][t * 8]), 16, 0, 0);
    __builtin_amdgcn_global_load_lds(
        (const __attribute__((address_space(1))) void*)(Bsrc + (long)rB1 * ldb + acol + kk),
        (__attribute__((address_space(3))) void*)(&Bs[bufSel][2048 + t * 8]), 16, 0, 0);
  };
  auto advance = [&]() { kk += 32; if (kk >= K) { kk = 0; Asrc += iA; Bsrc += iB; } };

  int nt = nInner * (K >> 5);
  f32x4 acc[4][4] = {};
  stage(0);
  advance();
  __syncthreads();
  for (int s = 0; s < nt; ++s) {
    int cur = s & 1;
    if (s + 1 < nt) { stage(cur ^ 1); advance(); }
    short8 af[4], bfr[4];
#pragma unroll
    for (int i = 0; i < 4; ++i)
      af[i] = *reinterpret_cast<const short8*>(&As[cur][(wm + i * 16 + l15) * 32 + q * 8]);
#pragma unroll
    for (int j = 0; j < 4; ++j)
      bfr[j] = *reinterpret_cast<const short8*>(&Bs[cur][(wn + j * 16 + l15) * 32 + q * 8]);
#pragma unroll
    for (int i = 0; i < 4; ++i)
#pragma unroll
      for (int j = 0; j < 4; ++j)
        acc[i][j] = __builtin_amdgcn_mfma_f32_16x16x32_bf16(af[i], bfr[j], acc[i][j], 0, 0, 0);
    __syncthreads();
  }

  long cb = d.cOff[br] + (long)z * d.sCz[br];
#pragma unroll
  for (int i = 0; i < 4; ++i)
#pragma unroll
    for (int j = 0; j < 4; ++j)
#pragma unroll
      for (int r = 0; r < 4; ++r) {
        float v = acc[i][j][r] * alpha;
        int rg = m0 + wm + i * 16 + q * 4 + r;
        int cg = n0 + wn + j * 16 + l15;
        if (cg < Ncl) {
          long idx = cb + (long)rg * ldc + cg;
          if (OUT_F32) ((float*)Cp)[idx] = v;
          else ((unsigned short*)Cp)[idx] = f2bf(v);
        }
      }
}

// ---------- host ----------
extern "C" void kernel_launch(void* const* d_in, const int* in_sizes, int n_in,
                              void* d_out, int out_size, void* d_ws, size_t ws_size,
                              hipStream_t stream) {
  const float* embs[4] = {(const float*)d_in[0], (const float*)d_in[1],
                          (const float*)d_in[2], (const float*)d_in[3]};
  const float* embA = (const float*)d_in[4];
  const float* Wq1  = (const float*)d_in[5];
  const float* Wq2  = (const float*)d_in[6];
  const float* Wq3  = (const float*)d_in[7];
  const float* Wq4  = (const float*)d_in[8];
  const float* Wk   = (const float*)d_in[9];
  const float* Wv   = (const float*)d_in[10];
  float* out = (float*)d_out;

  char* base = (char*)d_ws;
  size_t off = 0;
  auto take = [&](size_t bytes) -> void* {
    void* p = base + off;
    off += (bytes + 255) & ~(size_t)255;
    return p;
  };
  unsigned short* EA    = (unsigned short*)take(15728640);  // embA bf16 [8][1024][960]
  unsigned short* embAT = (unsigned short*)take(15728640);  // embA^T [8][960][1024]; CT aliases
  unsigned short* embTc = (unsigned short*)take(15728640);  // concat emb^T [8][960][1024]
  unsigned short* WQb   = (unsigned short*)take(2785280);   // Wq1..4 bf16
  unsigned short* WKb   = (unsigned short*)take(7372800);   // Wk bf16 [4][960][960]
  unsigned short* WvT   = (unsigned short*)take(7372800);   // Wv^T [4][960][960]
  unsigned short* WOb   = (unsigned short*)take(696320);    // Wo1..4 bf16
  float*          ST    = (float*)take(1024);               // stats [32][4][2] f32
  unsigned short* GT    = (unsigned short*)take(14745600);  // G [8][960][960]; SPW aliases
  unsigned short* Tbuf  = (unsigned short*)take(58982400);  // T [32][960][960]
  char*           SCr   = (char*)take(58982400);            // scores fp16 -> probs bf16 in place
  _Float16*       SC    = (_Float16*)SCr;
  unsigned short* PR    = (unsigned short*)SCr;             // probs bf16 [32][960][960]
  unsigned short* SPW   = GT;                               // [8][960][960]  (G dead after T)
  unsigned short* CT    = embAT;                            // [8][1024][960] (embAT dead after G)

  if (ws_size < off) return;  // fail clean instead of faulting

  hipMemsetAsync(ST, 0, 1024, stream);

  const long Cs[4]     = {64, 128, 256, 512};
  const long c0s[4]    = {0, 64, 192, 448};
  const long woOff[4]  = {0, 4096, 20480, 86016};
  const long outOff[4] = {0, 524288, 1572864, 3670016};
  const float kscale = 0.0322748612f;  // 1/sqrt(960)
  YDesc ydDummy = {};

  // plain casts
  cast4_kernel<<<4096, 256, 0, stream>>>(embA, 7864320, embA, 0, embA, 0, embA, 0, EA);
  cast4_kernel<<<1024, 256, 0, stream>>>(Wq1, 16384, Wq2, 65536, Wq3, 262144, Wq4, 1048576, WQb);
  cast4_kernel<<<1024, 256, 0, stream>>>(Wk, 3686400, Wk, 0, Wk, 0, Wk, 0, WKb);
  cast4_kernel<<<512, 256, 0, stream>>>((const float*)d_in[11], 4096, (const float*)d_in[12], 16384,
                                        (const float*)d_in[13], 65536, (const float*)d_in[14], 262144, WOb);
  // transpose-casts
  tcast_kernel<<<dim3(15, 16, 8), 256, 0, stream>>>(embA, embAT, 1024, 960, 983040, 983040);
  for (int i = 0; i < 4; ++i)
    tcast_kernel<<<dim3((int)Cs[i] / 64, 16, 8), 256, 0, stream>>>(
        embs[i], embTc + c0s[i] * 1024, 1024, (int)Cs[i], 1024 * Cs[i], 983040);
  tcast_kernel<<<dim3(15, 15, 4), 256, 0, stream>>>(Wv, WvT, 960, 960, 921600, 921600);

  // G[b][k][c] = sum_n embA[n,k]*emb_cat[n,c] : M=960, N=960, K=1024, z=8 (512 blocks)
  gemm_nt<128, 128, 0, 0, 0><<<dim3(8, 8, 8), 256, 0, stream>>>(
      embAT, embTc, GT, 1024, 1024, 1024, 960, 1,
      983040L, 0L, 983040L, 0L, 921600L,
      1, 0L, 0L, 1.0f, nullptr, 960, 960, 960, 960, 0, ydDummy);

  // T[b,h][cc][k] = Wq_br[h] @ G[b] (block-diagonal over branch rows), one launch
  {
    BDesc d;
    const int brOf[8]  = {0, 1, 2, 2, 3, 3, 3, 3};
    const int ar0[8]   = {0, 0, 0, 128, 0, 128, 256, 384};
    const long wqOff[4] = {0, 16384, 81920, 344064};
    for (int y = 0; y < 8; ++y) {
      int br = brOf[y];
      int Ci = (int)Cs[br];
      d.K[y] = Ci;
      d.aRow0[y] = ar0[y];
      d.out0[y] = (int)c0s[br] + ar0[y];
      d.mw[y] = (br == 0) ? 64 : 128;
      d.bc[y] = (int)c0s[br];
      d.aOff[y] = wqOff[br];
      d.aH[y] = (long)Ci * Ci;
    }
    gemm_bd<<<dim3(15, 8, 32), 256, 0, stream>>>(WQb, GT, Tbuf, 960, 921600L, 921600L, d);
  }

  // scores[b,h][cc][o] = kscale * T[b,h] @ Wk[h]^T, fp16 out + per-branch stats (2048 blocks)
  {
    YDesc yd;
    const int m0s[8] = {0, 64, 192, 320, 448, 576, 704, 832};
    const int mws[8] = {64, 128, 128, 128, 128, 128, 128, 128};
    const int brs[8] = {0, 1, 2, 2, 3, 3, 3, 3};
    for (int y = 0; y < 8; ++y) { yd.m0[y] = m0s[y]; yd.mw[y] = mws[y]; yd.br[y] = brs[y]; }
    gemm_nt<128, 128, 2, 1, 1><<<dim3(8, 8, 32), 256, 0, stream>>>(
        Tbuf, WKb, SC, 960, 960, 960, 960, 4,
        3686400L, 921600L, 0L, 921600L, 921600L,
        1, 0L, 0L, kscale, ST, 960, 960, 960, 960, 960, yd);
  }

  // instance-norm + softmax, in place (fp16 scores -> bf16 probs), one launch
  norm_softmax_all<<<dim3(32 * 960), 256, 0, stream>>>(SC, ST);

  // SPW[b][cc][k] = 0.25 * sum_h probs[b,h] @ WvT[h] : z=8, nInner=4 (512 blocks)
  gemm_nt<128, 128, 0, 0, 0><<<dim3(8, 8, 8), 256, 0, stream>>>(
      PR, WvT, SPW, 960, 960, 960, 960, 1,
      3686400L, 0L, 0L, 0L, 921600L,
      4, 921600L, 921600L, 0.25f, nullptr, 960, 960, 960, 960, 0, ydDummy);

  // CT[b][n][cc] = embA[b] @ SPW[b]^T : M=1024, N=960, K=960, z=8 (512 blocks)
  gemm_nt<128, 128, 0, 0, 0><<<dim3(8, 8, 8), 256, 0, stream>>>(
      EA, SPW, CT, 960, 960, 960, 960, 1,
      983040L, 0L, 921600L, 0L, 983040L,
      1, 0L, 0L, 1.0f, nullptr, 1024, 960, 1024, 960, 0, ydDummy);

  // out-all: out[b,n,c'] = CT[b][:, branch cols] @ Wo^T, one launch (512 blocks)
  {
    MDesc d;
    for (int i = 0; i < 4; ++i) {
      long C = Cs[i];
      d.aOff[i] = c0s[i];       d.sAz[i] = 983040L;          d.iA[i] = 0;
      d.bOff[i] = woOff[i];     d.sBz[i] = 0;                d.iB[i] = 0;
      d.cOff[i] = outOff[i];    d.sCz[i] = 1024L * C;
      d.lda[i] = 960; d.ldb[i] = (int)C; d.ldcv[i] = (int)C;
      d.Kk[i] = (int)C; d.Ncl[i] = (int)C; d.nIn[i] = 1;
      d.alpha[i] = 1.0f;
    }
    d.nstart[0] = 0; d.nstart[1] = 1; d.nstart[2] = 2; d.nstart[3] = 4;
    gemm_multi<1><<<dim3(8, 8, 8), 256, 0, stream>>>(CT, WOb, out, d);
  }
  (void)in_sizes; (void)n_in; (void)out_size;
}

// Round 6
// 512.307 us; speedup vs baseline: 1.5853x; 1.0029x over previous
//
#include <hip/hip_runtime.h>
#include <hip/hip_bf16.h>

// ---------- types ----------
typedef __attribute__((ext_vector_type(8))) short short8;
typedef __attribute__((ext_vector_type(4))) float f32x4;

static __device__ __forceinline__ unsigned short f2bf(float x) {
  union { __hip_bfloat16 h; unsigned short u; } cv;
  cv.h = __float2bfloat16(x);
  return cv.u;
}

template<int N> static __device__ __forceinline__ void waitcnt_vm() {
  if constexpr (N == 0) asm volatile("s_waitcnt vmcnt(0)" ::: "memory");
  else if constexpr (N == 3) asm volatile("s_waitcnt vmcnt(3)" ::: "memory");
  else if constexpr (N == 4) asm volatile("s_waitcnt vmcnt(4)" ::: "memory");
  else if constexpr (N == 6) asm volatile("s_waitcnt vmcnt(6)" ::: "memory");
  else if constexpr (N == 8) asm volatile("s_waitcnt vmcnt(8)" ::: "memory");
}

// XCD-chunked swizzle (T1): contiguous logical-tile ranges per XCD (nwg%8==0).
// Verified r3->r4: FETCH 545MB -> 65MB on the scores/SPW GEMMs.
static __device__ __forceinline__ void xcd_swizzle(unsigned& bx, unsigned& by, unsigned& bz) {
  unsigned nwg = gridDim.x * gridDim.y * gridDim.z;
  unsigned lin = blockIdx.x + gridDim.x * (blockIdx.y + gridDim.y * blockIdx.z);
  unsigned chunk = nwg >> 3;
  lin = (lin & 7) * chunk + (lin >> 3);
  bx = lin % gridDim.x;
  unsigned tmp = lin / gridDim.x;
  by = tmp % gridDim.y;
  bz = tmp / gridDim.y;
}

// ---------- cast fp32 -> bf16, up to 4 concatenated segments ----------
__global__ void cast4_kernel(const float* __restrict__ s0, long n0,
                             const float* __restrict__ s1, long n1,
                             const float* __restrict__ s2, long n2,
                             const float* __restrict__ s3, long n3,
                             unsigned short* __restrict__ dst) {
  long N4 = (n0 + n1 + n2 + n3) >> 2;
  for (long i = blockIdx.x * (long)blockDim.x + threadIdx.x; i < N4;
       i += (long)gridDim.x * blockDim.x) {
    long e = i << 2;
    const float* s; long j = e;
    if (j < n0) s = s0;
    else { j -= n0; if (j < n1) s = s1;
      else { j -= n1; if (j < n2) s = s2;
        else { j -= n2; s = s3; } } }
    float4 v = *reinterpret_cast<const float4*>(s + j);
    ushort4 o;
    o.x = f2bf(v.x); o.y = f2bf(v.y); o.z = f2bf(v.z); o.w = f2bf(v.w);
    *reinterpret_cast<ushort4*>(dst + e) = o;
  }
}

// ---------- transpose-cast: fp32 [R,C] -> bf16 [C,R], batched over z ----------
__global__ __launch_bounds__(256)
void tcast_kernel(const float* __restrict__ in, unsigned short* __restrict__ out,
                  int R, int C, long sIn, long sOut) {
  __shared__ float tile[64][65];
  int z = blockIdx.z;
  const float* src = in + (long)z * sIn;
  unsigned short* dst = out + (long)z * sOut;
  int r0 = blockIdx.y * 64, c0 = blockIdx.x * 64;
  int t = threadIdx.x;
  int lr = t >> 4;          // 0..15
  int lc = (t & 15) * 4;    // 0,4,..,60
#pragma unroll
  for (int j = 0; j < 4; ++j) {
    int r = lr + j * 16;
    float4 v = *reinterpret_cast<const float4*>(src + (long)(r0 + r) * C + c0 + lc);
    tile[r][lc] = v.x; tile[r][lc + 1] = v.y; tile[r][lc + 2] = v.z; tile[r][lc + 3] = v.w;
  }
  __syncthreads();
#pragma unroll
  for (int j = 0; j < 4; ++j) {
    int oc = lr + j * 16;
    ushort4 o;
    o.x = f2bf(tile[lc][oc]);
    o.y = f2bf(tile[lc + 1][oc]);
    o.z = f2bf(tile[lc + 2][oc]);
    o.w = f2bf(tile[lc + 3][oc]);
    *reinterpret_cast<ushort4*>(dst + (long)(c0 + oc) * R + r0 + lc) = o;
  }
}

// ---------- y-tile descriptor for branch-aligned tiling ----------
struct YDesc { int m0[8]; int mw[8]; int br[8]; };

// ---------- generic NT bf16 MFMA GEMM, TM x TN tile, 256 threads ----------
// Depth-2 prefetch pipeline (T3/T4): 4 LDS buffers; iteration s issues stage
// s+2, waits counted vmcnt (stage-s loads only; s+1/s+2 stay in flight across
// the barrier), ONE raw s_barrier per iteration. WAR-safe: buffer (s+2)&3 was
// last read in compute(s-2), complete before the iter s-1 barrier all waves
// passed. nInner folds a reduction (e.g. heads) by walking A/B by iA/iB.
template<int TM, int TN, int OUT, int DO_STATS, int YD>
__global__ __launch_bounds__(256)
void gemm_nt(const unsigned short* __restrict__ A,
             const unsigned short* __restrict__ B,
             void* __restrict__ Cp,
             int K, int lda, int ldb, long ldc, int Hdiv,
             long sAb, long sAh, long sBb, long sBh, long sC,
             int nInner, long iA, long iB,
             float alpha, float* __restrict__ stats,
             int Mclamp, int Nclamp, int Mwrite, int Nwrite, int Nvalid, YDesc yd) {
  constexpr int WM = TM / 32, WN = TN / 32;
  constexpr int L = TM / 64 + TN / 64;   // global_load_lds per thread per stage
  __shared__ unsigned short As[4][TM * 32];
  __shared__ unsigned short Bs[4][TN * 32];
  __shared__ float red[8];

  unsigned bxu, byu, bzu;
  xcd_swizzle(bxu, byu, bzu);
  int z = (int)bzu;
  int b = z / Hdiv, h = z % Hdiv;
  const unsigned short* Ab = A + (long)b * sAb + (long)h * sAh;
  const unsigned short* Bb = B + (long)b * sBb + (long)h * sBh;
  int y = (int)byu;
  int m0 = YD ? yd.m0[y] : y * TM;
  int rowLimit = YD ? (m0 + yd.mw[y]) : Mwrite;
  int n0 = (int)bxu * TN;
  int t = threadIdx.x;
  int lane = t & 63, wave = t >> 6;
  int wm = (wave >> 1) * (TM / 2), wn = (wave & 1) * (TN / 2);
  int l15 = lane & 15, q = lane >> 4;
  int arow = t >> 2, acol = (t & 3) * 8;

  int rA[TM / 64], rB[TN / 64];
#pragma unroll
  for (int r = 0; r < TM / 64; ++r) rA[r] = min(m0 + r * 64 + arow, Mclamp - 1);
#pragma unroll
  for (int r = 0; r < TN / 64; ++r) rB[r] = min(n0 + r * 64 + arow, Nclamp - 1);

  int kSteps = K >> 5;
  int nt = nInner * kSteps;
  const unsigned short* Asrc = Ab;
  const unsigned short* Bsrc = Bb;
  int kk = 0;

  auto stage = [&](int bufSel) {
#pragma unroll
    for (int r = 0; r < TM / 64; ++r)
      __builtin_amdgcn_global_load_lds(
          (const __attribute__((address_space(1))) void*)(Asrc + (long)rA[r] * lda + acol + kk),
          (__attribute__((address_space(3))) void*)(&As[bufSel][r * 2048 + t * 8]), 16, 0, 0);
#pragma unroll
    for (int r = 0; r < TN / 64; ++r)
      __builtin_amdgcn_global_load_lds(
          (const __attribute__((address_space(1))) void*)(Bsrc + (long)rB[r] * ldb + acol + kk),
          (__attribute__((address_space(3))) void*)(&Bs[bufSel][r * 2048 + t * 8]), 16, 0, 0);
    kk += 32; if (kk >= K) { kk = 0; Asrc += iA; Bsrc += iB; }
  };

  f32x4 acc[WM][WN] = {};
  stage(0);
  if (nt > 1) stage(1);
  for (int s = 0; s < nt; ++s) {
    if (s + 2 < nt) stage((s + 2) & 3);
    int rem = nt - 1 - s;
    if (rem >= 2) waitcnt_vm<2 * L>();
    else if (rem == 1) waitcnt_vm<L>();
    else waitcnt_vm<0>();
    __builtin_amdgcn_s_barrier();
    __builtin_amdgcn_sched_barrier(0);
    const unsigned short* Ac = As[s & 3];
    const unsigned short* Bc = Bs[s & 3];
    short8 af[WM], bfr[WN];
#pragma unroll
    for (int i = 0; i < WM; ++i)
      af[i] = *reinterpret_cast<const short8*>(Ac + (wm + i * 16 + l15) * 32 + q * 8);
#pragma unroll
    for (int j = 0; j < WN; ++j)
      bfr[j] = *reinterpret_cast<const short8*>(Bc + (wn + j * 16 + l15) * 32 + q * 8);
#pragma unroll
    for (int i = 0; i < WM; ++i)
#pragma unroll
      for (int j = 0; j < WN; ++j)
        acc[i][j] = __builtin_amdgcn_mfma_f32_16x16x32_bf16(af[i], bfr[j], acc[i][j], 0, 0, 0);
  }

  long cbase = (long)z * sC;
  float ssum = 0.f, ssq = 0.f;
#pragma unroll
  for (int i = 0; i < WM; ++i)
#pragma unroll
    for (int j = 0; j < WN; ++j)
#pragma unroll
      for (int r = 0; r < 4; ++r) {
        float v = acc[i][j][r] * alpha;
        int rg = m0 + wm + i * 16 + q * 4 + r;
        int cg = n0 + wn + j * 16 + l15;
        if (rg < rowLimit && cg < Nwrite) {
          long idx = cbase + (long)rg * ldc + cg;
          if (OUT == 1) ((float*)Cp)[idx] = v;
          else if (OUT == 2) ((_Float16*)Cp)[idx] = (_Float16)v;
          else ((unsigned short*)Cp)[idx] = f2bf(v);
        }
        if (DO_STATS && rg < rowLimit && cg < Nvalid) { ssum += v; ssq += v * v; }
      }

  if (DO_STATS) {
#pragma unroll
    for (int o = 32; o; o >>= 1) {
      ssum += __shfl_down(ssum, o, 64);
      ssq  += __shfl_down(ssq,  o, 64);
    }
    if (lane == 0) { red[wave] = ssum; red[wave + 4] = ssq; }
    __syncthreads();
    if (t == 0) {
      long slot = YD ? ((long)z * 8 + yd.br[y] * 2) : ((long)z * 2);
      atomicAdd(stats + slot,     red[0] + red[1] + red[2] + red[3]);
      atomicAdd(stats + slot + 1, red[4] + red[5] + red[6] + red[7]);
    }
  }
}

// ---------- block-diagonal A GEMM: T[b,h] = Wq_br[h] @ G[b] (per y-tile branch) ----------
struct BDesc { int K[8]; int aRow0[8]; int out0[8]; int mw[8]; int bc[8]; long aOff[8]; long aH[8]; };

__global__ __launch_bounds__(256)
void gemm_bd(const unsigned short* __restrict__ A0,
             const unsigned short* __restrict__ B0,
             unsigned short* __restrict__ Cp,
             int ldb, long sBz, long sC, BDesc d) {
  constexpr int TM = 128, TN = 64, WM = 4, WN = 2;
  __shared__ unsigned short As[4][TM * 32];
  __shared__ unsigned short Bs[4][TN * 32];
  unsigned bxu, byu, bzu;
  xcd_swizzle(bxu, byu, bzu);
  int z = (int)bzu;
  int b = z >> 2, h = z & 3;
  int y = (int)byu;
  int K = d.K[y];
  const unsigned short* Ab = A0 + d.aOff[y] + (long)h * d.aH[y];
  const unsigned short* Bb = B0 + (long)b * sBz + d.bc[y];
  int n0 = (int)bxu * TN;
  int t = threadIdx.x;
  int lane = t & 63, wave = t >> 6;
  int wm = (wave >> 1) * 64, wn = (wave & 1) * 32;
  int l15 = lane & 15, q = lane >> 4;
  int arow = t >> 2, acol = (t & 3) * 8;

  int rA0 = min(d.aRow0[y] + arow, K - 1);
  int rA1 = min(d.aRow0[y] + 64 + arow, K - 1);
  int rB0 = n0 + arow;

  int kk = 0;
  auto stage = [&](int bufSel) {
    __builtin_amdgcn_global_load_lds(
        (const __attribute__((address_space(1))) void*)(Ab + (long)rA0 * K + acol + kk),
        (__attribute__((address_space(3))) void*)(&As[bufSel][t * 8]), 16, 0, 0);
    __builtin_amdgcn_global_load_lds(
        (const __attribute__((address_space(1))) void*)(Ab + (long)rA1 * K + acol + kk),
        (__attribute__((address_space(3))) void*)(&As[bufSel][2048 + t * 8]), 16, 0, 0);
    __builtin_amdgcn_global_load_lds(
        (const __attribute__((address_space(1))) void*)(Bb + (long)rB0 * ldb + acol + kk),
        (__attribute__((address_space(3))) void*)(&Bs[bufSel][t * 8]), 16, 0, 0);
    kk += 32;
  };

  int nt = K >> 5;
  f32x4 acc[WM][WN] = {};
  stage(0);
  if (nt > 1) stage(1);
  for (int s = 0; s < nt; ++s) {
    if (s + 2 < nt) stage((s + 2) & 3);
    int rem = nt - 1 - s;
    if (rem >= 2) waitcnt_vm<6>();
    else if (rem == 1) waitcnt_vm<3>();
    else waitcnt_vm<0>();
    __builtin_amdgcn_s_barrier();
    __builtin_amdgcn_sched_barrier(0);
    const unsigned short* Ac = As[s & 3];
    const unsigned short* Bc = Bs[s & 3];
    short8 af[WM], bfr[WN];
#pragma unroll
    for (int i = 0; i < WM; ++i)
      af[i] = *reinterpret_cast<const short8*>(Ac + (wm + i * 16 + l15) * 32 + q * 8);
#pragma unroll
    for (int j = 0; j < WN; ++j)
      bfr[j] = *reinterpret_cast<const short8*>(Bc + (wn + j * 16 + l15) * 32 + q * 8);
#pragma unroll
    for (int i = 0; i < WM; ++i)
#pragma unroll
      for (int j = 0; j < WN; ++j)
        acc[i][j] = __builtin_amdgcn_mfma_f32_16x16x32_bf16(af[i], bfr[j], acc[i][j], 0, 0, 0);
  }

  long cbase = (long)z * sC;
  int mw = d.mw[y], out0 = d.out0[y];
#pragma unroll
  for (int i = 0; i < WM; ++i)
#pragma unroll
    for (int j = 0; j < WN; ++j)
#pragma unroll
      for (int r = 0; r < 4; ++r) {
        int loc = wm + i * 16 + q * 4 + r;
        int cg = n0 + wn + j * 16 + l15;
        if (loc < mw) {
          long idx = cbase + (long)(out0 + loc) * 960 + cg;
          Cp[idx] = f2bf(acc[i][j][r]);
        }
      }
}

// ---------- instance-norm + softmax over KV=960, in-place fp16 -> bf16 ----------
__global__ __launch_bounds__(256)
void norm_softmax_all(_Float16* __restrict__ S, const float* __restrict__ stats) {
  long row = blockIdx.x;            // z*960 + cc
  int z = (int)(row / 960), cc = (int)(row % 960);
  int br = (cc < 64) ? 0 : (cc < 192) ? 1 : (cc < 448) ? 2 : 3;
  int Cbr = (br == 0) ? 64 : (br == 1) ? 128 : (br == 2) ? 256 : 512;
  float invCnt = 1.0f / ((float)Cbr * 960.0f);
  float m1 = stats[z * 8 + br * 2 + 0] * invCnt;
  float m2 = stats[z * 8 + br * 2 + 1] * invCnt;
  float rsig = rsqrtf(m2 - m1 * m1 + 1e-5f);
  _Float16* s = S + row * 960;
  int t = threadIdx.x;
  float e[4]; float acc = 0.f;
#pragma unroll
  for (int j = 0; j < 4; ++j) {
    int i = t + j * 256;
    if (i < 960) { e[j] = __expf(((float)s[i] - m1) * rsig); acc += e[j]; }
    else e[j] = 0.f;
  }
#pragma unroll
  for (int o = 32; o; o >>= 1) acc += __shfl_down(acc, o, 64);
  __shared__ float red[4];
  if ((t & 63) == 0) red[t >> 6] = acc;
  __syncthreads();
  float inv = 1.0f / (red[0] + red[1] + red[2] + red[3]);
  unsigned short* p = (unsigned short*)s;
#pragma unroll
  for (int j = 0; j < 4; ++j) {
    int i = t + j * 256;
    if (i < 960) p[i] = f2bf(e[j] * inv);
  }
}

// ---------- 4-branch batched NT GEMM (out-proj), branch from bx ----------
struct MDesc {
  long aOff[4], bOff[4], cOff[4];
  long sAz[4], sBz[4], sCz[4];
  long iA[4], iB[4];
  int  lda[4], ldb[4], ldcv[4];
  int  Kk[4], Ncl[4], nIn[4];
  int  nstart[4];
  float alpha[4];
};

template<int OUT_F32>
__global__ __launch_bounds__(256)
void gemm_multi(const unsigned short* __restrict__ A0,
                const unsigned short* __restrict__ B0,
                void* __restrict__ Cp, MDesc d) {
  __shared__ unsigned short As[4][128 * 32];
  __shared__ unsigned short Bs[4][128 * 32];
  unsigned bxu, byu, bzu;
  xcd_swizzle(bxu, byu, bzu);
  int bx = (int)bxu;
  int br = (bx >= d.nstart[3]) ? 3 : (bx >= d.nstart[2]) ? 2 : (bx >= d.nstart[1]) ? 1 : 0;
  int z = (int)bzu;
  int n0 = (bx - d.nstart[br]) * 128;
  int m0 = (int)byu * 128;
  int K = d.Kk[br], lda = d.lda[br], ldb = d.ldb[br], ldc = d.ldcv[br];
  int Ncl = d.Ncl[br], nInner = d.nIn[br];
  long iA = d.iA[br], iB = d.iB[br];
  float alpha = d.alpha[br];
  const unsigned short* Ab = A0 + d.aOff[br] + (long)z * d.sAz[br];
  const unsigned short* Bb = B0 + d.bOff[br] + (long)z * d.sBz[br];

  int t = threadIdx.x, lane = t & 63, wave = t >> 6;
  int wm = (wave >> 1) * 64, wn = (wave & 1) * 64;
  int l15 = lane & 15, q = lane >> 4;
  int arow = t >> 2, acol = (t & 3) * 8;
  int rA0 = m0 + arow, rA1 = m0 + 64 + arow;
  int rB0 = min(n0 + arow, Ncl - 1), rB1 = min(n0 + 64 + arow, Ncl - 1);

  const unsigned short* Asrc = Ab;
  const unsigned short* Bsrc = Bb;
  int kk = 0;
  auto stage = [&](int bufSel) {
    __builtin_amdgcn_global_load_lds(
        (const __attribute__((address_space(1))) void*)(Asrc + (long)rA0 * lda + acol + kk),
        (__attribute__((address_space(3))) void*)(&As[bufSel][t * 8]), 16, 0, 0);
    __builtin_amdgcn_global_load_lds(
        (const __attribute__((address_space(1))) void*)(Asrc + (long)rA1 * lda + acol + kk),
        (__attribute__((address_space(3))) void*)(&As[bufSel][2048 + t * 8]), 16, 0, 0);
    __builtin_amdgcn_global_load_lds(
        (const __attribute__((address_space(1))) void*)(Bsrc + (long)rB0 * ldb + acol + kk),
        (__attribute__((address_space(3))) void*)(&Bs[bufSel][t * 8]), 16, 0, 0);
    __builtin_amdgcn_global_load_lds(
        (const __attribute__((address_space(1))) void*)(Bsrc + (long)rB1 * ldb + acol + kk),
        (__attribute__((address_space(3))) void*)(&Bs[bufSel][2048 + t * 8]), 16, 0, 0);
    kk += 32; if (kk >= K) { kk = 0; Asrc += iA; Bsrc += iB; }
  };

  int nt = nInner * (K >> 5);
  f32x4 acc[4][4] = {};
  stage(0);
  if (nt > 1) stage(1);
  for (int s = 0; s < nt; ++s) {
    if (s + 2 < nt) stage((s + 2) & 3);
    int rem = nt - 1 - s;
    if (rem >= 2) waitcnt_vm<8>();
    else if (rem == 1) waitcnt_vm<4>();
    else waitcnt_vm<0>();
    __builtin_amdgcn_s_barrier();
    __builtin_amdgcn_sched_barrier(0);
    const unsigned short* Ac = As[s & 3];
    const unsigned short* Bc = Bs[s & 3];
    short8 af[4], bfr[4];
#pragma unroll
    for (int i = 0; i < 4; ++i)
      af[i] = *reinterpret_cast<const short8*>(Ac + (wm + i * 16 + l15) * 32 + q * 8);
#pragma unroll
    for (int j = 0; j < 4; ++j)
      bfr[j] = *reinterpret_cast<const short8*>(Bc + (wn + j * 16 + l15) * 32 + q * 8);
#pragma unroll
    for (int i = 0; i < 4; ++i)
#pragma unroll
      for (int j = 0; j < 4; ++j)
        acc[i][j] = __builtin_amdgcn_mfma_f32_16x16x32_bf16(af[i], bfr[j], acc[i][j], 0, 0, 0);
  }

  long cb = d.cOff[br] + (long)z * d.sCz[br];
#pragma unroll
  for (int i = 0; i < 4; ++i)
#pragma unroll
    for (int j = 0; j < 4; ++j)
#pragma unroll
      for (int r = 0; r < 4; ++r) {
        float v = acc[i][j][r] * alpha;
        int rg = m0 + wm + i * 16 + q * 4 + r;
        int cg = n0 + wn + j * 16 + l15;
        if (cg < Ncl) {
          long idx = cb + (long)rg * ldc + cg;
          if (OUT_F32) ((float*)Cp)[idx] = v;
          else ((unsigned short*)Cp)[idx] = f2bf(v);
        }
      }
}

// ---------- host ----------
extern "C" void kernel_launch(void* const* d_in, const int* in_sizes, int n_in,
                              void* d_out, int out_size, void* d_ws, size_t ws_size,
                              hipStream_t stream) {
  const float* embs[4] = {(const float*)d_in[0], (const float*)d_in[1],
                          (const float*)d_in[2], (const float*)d_in[3]};
  const float* embA = (const float*)d_in[4];
  const float* Wq1  = (const float*)d_in[5];
  const float* Wq2  = (const float*)d_in[6];
  const float* Wq3  = (const float*)d_in[7];
  const float* Wq4  = (const float*)d_in[8];
  const float* Wk   = (const float*)d_in[9];
  const float* Wv   = (const float*)d_in[10];
  float* out = (float*)d_out;

  char* base = (char*)d_ws;
  size_t off = 0;
  auto take = [&](size_t bytes) -> void* {
    void* p = base + off;
    off += (bytes + 255) & ~(size_t)255;
    return p;
  };
  unsigned short* EA    = (unsigned short*)take(15728640);  // embA bf16 [8][1024][960]
  unsigned short* embAT = (unsigned short*)take(15728640);  // embA^T [8][960][1024]; CT aliases
  unsigned short* embTc = (unsigned short*)take(15728640);  // concat emb^T [8][960][1024]
  unsigned short* WQb   = (unsigned short*)take(2785280);   // Wq1..4 bf16
  unsigned short* WKb   = (unsigned short*)take(7372800);   // Wk bf16 [4][960][960]
  unsigned short* WvT   = (unsigned short*)take(7372800);   // Wv^T [4][960][960]
  unsigned short* WOb   = (unsigned short*)take(696320);    // Wo1..4 bf16
  float*          ST    = (float*)take(1024);               // stats [32][4][2] f32
  unsigned short* GT    = (unsigned short*)take(14745600);  // G [8][960][960]; SPW aliases
  unsigned short* Tbuf  = (unsigned short*)take(58982400);  // T [32][960][960]
  char*           SCr   = (char*)take(58982400);            // scores fp16 -> probs bf16 in place
  _Float16*       SC    = (_Float16*)SCr;
  unsigned short* PR    = (unsigned short*)SCr;             // probs bf16 [32][960][960]
  unsigned short* SPW   = GT;                               // [8][960][960]  (G dead after T)
  unsigned short* CT    = embAT;                            // [8][1024][960] (embAT dead after G)

  if (ws_size < off) return;  // fail clean instead of faulting

  hipMemsetAsync(ST, 0, 1024, stream);

  const long Cs[4]     = {64, 128, 256, 512};
  const long c0s[4]    = {0, 64, 192, 448};
  const long woOff[4]  = {0, 4096, 20480, 86016};
  const long outOff[4] = {0, 524288, 1572864, 3670016};
  const float kscale = 0.0322748612f;  // 1/sqrt(960)
  YDesc ydDummy = {};

  // plain casts
  cast4_kernel<<<4096, 256, 0, stream>>>(embA, 7864320, embA, 0, embA, 0, embA, 0, EA);
  cast4_kernel<<<1024, 256, 0, stream>>>(Wq1, 16384, Wq2, 65536, Wq3, 262144, Wq4, 1048576, WQb);
  cast4_kernel<<<1024, 256, 0, stream>>>(Wk, 3686400, Wk, 0, Wk, 0, Wk, 0, WKb);
  cast4_kernel<<<512, 256, 0, stream>>>((const float*)d_in[11], 4096, (const float*)d_in[12], 16384,
                                        (const float*)d_in[13], 65536, (const float*)d_in[14], 262144, WOb);
  // transpose-casts
  tcast_kernel<<<dim3(15, 16, 8), 256, 0, stream>>>(embA, embAT, 1024, 960, 983040, 983040);
  for (int i = 0; i < 4; ++i)
    tcast_kernel<<<dim3((int)Cs[i] / 64, 16, 8), 256, 0, stream>>>(
        embs[i], embTc + c0s[i] * 1024, 1024, (int)Cs[i], 1024 * Cs[i], 983040);
  tcast_kernel<<<dim3(15, 15, 4), 256, 0, stream>>>(Wv, WvT, 960, 960, 921600, 921600);

  // G[b][k][c] = sum_n embA[n,k]*emb_cat[n,c] : M=960, N=960, K=1024, z=8 (512 blocks)
  gemm_nt<128, 128, 0, 0, 0><<<dim3(8, 8, 8), 256, 0, stream>>>(
      embAT, embTc, GT, 1024, 1024, 1024, 960, 1,
      983040L, 0L, 983040L, 0L, 921600L,
      1, 0L, 0L, 1.0f, nullptr, 960, 960, 960, 960, 0, ydDummy);

  // T[b,h][cc][k] = Wq_br[h] @ G[b] (block-diagonal over branch rows), one launch
  {
    BDesc d;
    const int brOf[8]  = {0, 1, 2, 2, 3, 3, 3, 3};
    const int ar0[8]   = {0, 0, 0, 128, 0, 128, 256, 384};
    const long wqOff[4] = {0, 16384, 81920, 344064};
    for (int y = 0; y < 8; ++y) {
      int br = brOf[y];
      int Ci = (int)Cs[br];
      d.K[y] = Ci;
      d.aRow0[y] = ar0[y];
      d.out0[y] = (int)c0s[br] + ar0[y];
      d.mw[y] = (br == 0) ? 64 : 128;
      d.bc[y] = (int)c0s[br];
      d.aOff[y] = wqOff[br];
      d.aH[y] = (long)Ci * Ci;
    }
    gemm_bd<<<dim3(15, 8, 32), 256, 0, stream>>>(WQb, GT, Tbuf, 960, 921600L, 921600L, d);
  }

  // scores[b,h][cc][o] = kscale * T[b,h] @ Wk[h]^T, fp16 out + per-branch stats (2048 blocks)
  {
    YDesc yd;
    const int m0s[8] = {0, 64, 192, 320, 448, 576, 704, 832};
    const int mws[8] = {64, 128, 128, 128, 128, 128, 128, 128};
    const int brs[8] = {0, 1, 2, 2, 3, 3, 3, 3};
    for (int y = 0; y < 8; ++y) { yd.m0[y] = m0s[y]; yd.mw[y] = mws[y]; yd.br[y] = brs[y]; }
    gemm_nt<128, 128, 2, 1, 1><<<dim3(8, 8, 32), 256, 0, stream>>>(
        Tbuf, WKb, SC, 960, 960, 960, 960, 4,
        3686400L, 921600L, 0L, 921600L, 921600L,
        1, 0L, 0L, kscale, ST, 960, 960, 960, 960, 960, yd);
  }

  // instance-norm + softmax, in place (fp16 scores -> bf16 probs), one launch
  norm_softmax_all<<<dim3(32 * 960), 256, 0, stream>>>(SC, ST);

  // SPW[b][cc][k] = 0.25 * sum_h probs[b,h] @ WvT[h] : z=8, nInner=4 (512 blocks)
  gemm_nt<128, 128, 0, 0, 0><<<dim3(8, 8, 8), 256, 0, stream>>>(
      PR, WvT, SPW, 960, 960, 960, 960, 1,
      3686400L, 0L, 0L, 0L, 921600L,
      4, 921600L, 921600L, 0.25f, nullptr, 960, 960, 960, 960, 0, ydDummy);

  // CT[b][n][cc] = embA[b] @ SPW[b]^T : M=1024, N=960, K=960, z=8 (512 blocks)
  gemm_nt<128, 128, 0, 0, 0><<<dim3(8, 8, 8), 256, 0, stream>>>(
      EA, SPW, CT, 960, 960, 960, 960, 1,
      983040L, 0L, 921600L, 0L, 983040L,
      1, 0L, 0L, 1.0f, nullptr, 1024, 960, 1024, 960, 0, ydDummy);

  // out-all: out[b,n,c'] = CT[b][:, branch cols] @ Wo^T, one launch (512 blocks)
  {
    MDesc d;
    for (int i = 0; i < 4; ++i) {
      long C = Cs[i];
      d.aOff[i] = c0s[i];       d.sAz[i] = 983040L;          d.iA[i] = 0;
      d.bOff[i] = woOff[i];     d.sBz[i] = 0;                d.iB[i] = 0;
      d.cOff[i] = outOff[i];    d.sCz[i] = 1024L * C;
      d.lda[i] = 960; d.ldb[i] = (int)C; d.ldcv[i] = (int)C;
      d.Kk[i] = (int)C; d.Ncl[i] = (int)C; d.nIn[i] = 1;
      d.alpha[i] = 1.0f;
    }
    d.nstart[0] = 0; d.nstart[1] = 1; d.nstart[2] = 2; d.nstart[3] = 4;
    gemm_multi<1><<<dim3(8, 8, 8), 256, 0, stream>>>(CT, WOb, out, d);
  }
  (void)in_sizes; (void)n_in; (void)out_size;
}